// Round 11
// baseline (88.139 us; speedup 1.0000x reference)
//
#include <hip/hip_runtime.h>

// Problem constants
#define NTOK   (64 * 4096)   // B*S tokens
#define DDIM   64            // num_dim
#define NCLUST 256           // num_clusters
#define NFEAT  7             // continuous features
#define RT     2             // row-tiles of 16 tokens per wave
#define BLK    512           // threads per block (8 waves)
// tokens per block = 8 waves * RT*16 = 256 ; grid = 1024

typedef _Float16 f16x8 __attribute__((ext_vector_type(8)));
typedef float    f32x4 __attribute__((ext_vector_type(4)));

// -2 * (log2 e)^2 : folds softmax exp into exp2 and the -2 dot factor
#define KNEG2K (-4.1627379924399795f)

// ws layout: [0, 2048) float pre[512] = c2[256] ++ cw[256]
//            [2048, 2048+65536) _Float16 cent_swz[256*128]
// cent_swz row c: 16 chunks of 8 halves (16B):
//   chunk j in [0,8):  f16-hi of cent[c][j*8 .. j*8+8)
//   chunk j in [8,16): f16-lo of cent[c][(j-8)*8 .. +8)
// stored at chunk position (j ^ (c&7))  [XOR swizzle for ds_read_b128]

// ---- kernel 1a: per-cluster c2 / cw (verified R3/R5/R6, verbatim) ----
__global__ __launch_bounds__(NCLUST) void precompute_kernel(
    const float* __restrict__ centroids,
    const float* __restrict__ W2,
    float* __restrict__ pre) {
  const int c = threadIdx.x;
  const float4* cp = (const float4*)(centroids + c * DDIM);
  const float4* wp = (const float4*)W2;
  float c2a = 0.f, c2b = 0.f, cwa = 0.f, cwb = 0.f;
#pragma unroll
  for (int i = 0; i < DDIM / 4; i += 2) {
    float4 v0 = cp[i], v1 = cp[i + 1];
    float4 w0 = wp[i], w1 = wp[i + 1];
    c2a = fmaf(v0.x, v0.x, fmaf(v0.y, v0.y, fmaf(v0.z, v0.z, fmaf(v0.w, v0.w, c2a))));
    c2b = fmaf(v1.x, v1.x, fmaf(v1.y, v1.y, fmaf(v1.z, v1.z, fmaf(v1.w, v1.w, c2b))));
    cwa = fmaf(v0.x, w0.x, fmaf(v0.y, w0.y, fmaf(v0.z, w0.z, fmaf(v0.w, w0.w, cwa))));
    cwb = fmaf(v1.x, w1.x, fmaf(v1.y, w1.y, fmaf(v1.z, w1.z, fmaf(v1.w, w1.w, cwb))));
  }
  pre[c] = c2a + c2b;
  pre[NCLUST + c] = cwa + cwb;
}

// ---- kernel 1b: f16 hi/lo split -> XOR-swizzled chunk layout (verified R5/R6) ----
__global__ __launch_bounds__(256) void split_kernel(
    const float* __restrict__ centroids,
    _Float16* __restrict__ cent_swz) {
  const int tid = blockIdx.x * 256 + threadIdx.x;  // 0..4095
  const int c = tid >> 4;
  const int j = tid & 15;
  const int d0 = (j & 7) * 8;
  const bool lo = (j >= 8);
  f16x8 v;
#pragma unroll
  for (int i = 0; i < 8; ++i) {
    const float f = centroids[c * DDIM + d0 + i];
    const _Float16 h = (_Float16)f;
    v[i] = lo ? (_Float16)(f - (float)h) : h;
  }
  *(f16x8*)&cent_swz[c * 128 + (j ^ (c & 7)) * 8] = v;
}

// ---- kernel 2: fused main kernel ----
// 8 waves/block (512 thr), wave = 32 tokens (RT=2) x 256 clusters.
// LDS = EXACTLY 65536 B (centroid table only): R10 evidence shows 65536 ->
// 2 blocks/CU but 67584 -> 1 block/CU (occupancy 23%). c2/cw from global
// (L1-resident, verified R6 path). (512,2) => 128-VGPR cap; K-loop unroll=2
// bounds live B-fragments (R9: full unroll spilled 1.27GB).
__global__ __launch_bounds__(BLK, 2) void main_kernel(
    const float* __restrict__ x,
    const float* __restrict__ W_embed,
    const float* __restrict__ b_embed,
    const float* __restrict__ emb_table,
    const float* __restrict__ b2,
    const float* __restrict__ pre,
    const _Float16* __restrict__ cent_swz,
    float* __restrict__ out) {
  extern __shared__ _Float16 s_cent[];   // 256*128 halves = 65536 B exactly

  const int tid  = threadIdx.x;
  const int lane = tid & 63;
  const int wv   = tid >> 6;          // wave in block: 0..7
  const int col  = lane & 15;         // A-row (token) / B,C-col (cluster)
  const int g    = lane >> 4;         // k-group (0..3)
  const int tokBase = blockIdx.x * (8 * 16 * RT) + wv * (16 * RT);

  // ---- stage cent_swz (64KB) -> LDS ----
  {
    const float4* gsrc = (const float4*)cent_swz;   // 4096 float4
    float4* ldst = (float4*)s_cent;
#pragma unroll
    for (int i = 0; i < 8; ++i)
      ldst[tid + BLK * i] = gsrc[tid + BLK * i];
  }

  // ---- b_embed fragment (token-independent) ----
  const float4* br = (const float4*)b_embed;
  const float4 q0 = br[2 * g], q1 = br[2 * g + 1];
  const float4 q2 = br[8 + 2 * g], q3 = br[8 + 2 * g + 1];

  // ---- prologue: h[rt][0..7]=dims[g*8..+8), h[rt][8..15]=dims[32+g*8..+8) ----
  float h[RT][16];
  float xf[RT][NFEAT];
#pragma unroll
  for (int rt = 0; rt < RT; ++rt) {
    const int tok = tokBase + rt * 16 + col;
    const float4* xp = (const float4*)(x + (size_t)tok * 8);
    const float4 xa = xp[0], xb = xp[1];
    xf[rt][0] = xa.x; xf[rt][1] = xa.y; xf[rt][2] = xa.z; xf[rt][3] = xa.w;
    xf[rt][4] = xb.x; xf[rt][5] = xb.y; xf[rt][6] = xb.z;
    const int idx = (int)xb.w;
    const float4* er = (const float4*)(emb_table + (size_t)idx * DDIM);
    const float4 e0 = er[2 * g], e1 = er[2 * g + 1];
    const float4 e2 = er[8 + 2 * g], e3 = er[8 + 2 * g + 1];
    h[rt][0]  = e0.x + q0.x; h[rt][1]  = e0.y + q0.y;
    h[rt][2]  = e0.z + q0.z; h[rt][3]  = e0.w + q0.w;
    h[rt][4]  = e1.x + q1.x; h[rt][5]  = e1.y + q1.y;
    h[rt][6]  = e1.z + q1.z; h[rt][7]  = e1.w + q1.w;
    h[rt][8]  = e2.x + q2.x; h[rt][9]  = e2.y + q2.y;
    h[rt][10] = e2.z + q2.z; h[rt][11] = e2.w + q2.w;
    h[rt][12] = e3.x + q3.x; h[rt][13] = e3.y + q3.y;
    h[rt][14] = e3.z + q3.z; h[rt][15] = e3.w + q3.w;
  }
  // W_embed: f outer (W fragment loaded once), rt inner
#pragma unroll
  for (int f = 0; f < NFEAT; ++f) {
    const float4* wr = (const float4*)(W_embed + f * DDIM);
    const float4 w0 = wr[2 * g], w1 = wr[2 * g + 1];
    const float4 w2 = wr[8 + 2 * g], w3 = wr[8 + 2 * g + 1];
#pragma unroll
    for (int rt = 0; rt < RT; ++rt) {
      const float xv = xf[rt][f];
      h[rt][0]  = fmaf(xv, w0.x, h[rt][0]);  h[rt][1]  = fmaf(xv, w0.y, h[rt][1]);
      h[rt][2]  = fmaf(xv, w0.z, h[rt][2]);  h[rt][3]  = fmaf(xv, w0.w, h[rt][3]);
      h[rt][4]  = fmaf(xv, w1.x, h[rt][4]);  h[rt][5]  = fmaf(xv, w1.y, h[rt][5]);
      h[rt][6]  = fmaf(xv, w1.z, h[rt][6]);  h[rt][7]  = fmaf(xv, w1.w, h[rt][7]);
      h[rt][8]  = fmaf(xv, w2.x, h[rt][8]);  h[rt][9]  = fmaf(xv, w2.y, h[rt][9]);
      h[rt][10] = fmaf(xv, w2.z, h[rt][10]); h[rt][11] = fmaf(xv, w2.w, h[rt][11]);
      h[rt][12] = fmaf(xv, w3.x, h[rt][12]); h[rt][13] = fmaf(xv, w3.y, h[rt][13]);
      h[rt][14] = fmaf(xv, w3.z, h[rt][14]); h[rt][15] = fmaf(xv, w3.w, h[rt][15]);
    }
  }

  // ---- per-rt: h2 reduce (pre-scaled by -0.5) + f16 hi/lo split, NAMED frags ----
  f16x8 ah0_0, al0_0, ah1_0, al1_0; float nhb_0[4];
  f16x8 ah0_1, al0_1, ah1_1, al1_1; float nhb_1[4];

#define SPLIT_RT(RTI, AH0, AL0, AH1, AL1, NHB) do {                         \
    float ptl = 0.f;                                                        \
    _Pragma("unroll") for (int i = 0; i < 8; ++i) {                         \
      ptl = fmaf(h[RTI][i], h[RTI][i], ptl);                                \
      ptl = fmaf(h[RTI][8 + i], h[RTI][8 + i], ptl);                        \
    }                                                                       \
    ptl += __shfl_xor(ptl, 16);                                             \
    ptl += __shfl_xor(ptl, 32);                                             \
    ptl *= -0.5f;                                                           \
    _Pragma("unroll") for (int r = 0; r < 4; ++r)                           \
      NHB[r] = __shfl(ptl, g * 4 + r);                                      \
    _Pragma("unroll") for (int i = 0; i < 8; ++i) {                         \
      _Float16 t0 = (_Float16)h[RTI][i];                                    \
      AH0[i] = t0; AL0[i] = (_Float16)(h[RTI][i] - (float)t0);              \
      _Float16 t1 = (_Float16)h[RTI][8 + i];                                \
      AH1[i] = t1; AL1[i] = (_Float16)(h[RTI][8 + i] - (float)t1);          \
    }                                                                       \
  } while (0)

  SPLIT_RT(0, ah0_0, al0_0, ah1_0, al1_0, nhb_0);
  SPLIT_RT(1, ah0_1, al0_1, ah1_1, al1_1, nhb_1);
#undef SPLIT_RT

  __syncthreads();   // LDS stage complete

  // ---- loop-invariant LDS addressing (sw = (t*16+col)&7 = col&7) ----
  const int sw  = col & 7;
  const _Float16* base0 = s_cent + col * 128 + ((g) ^ sw) * 8;        // hi chunk a
  const _Float16* base1 = s_cent + col * 128 + ((4 + g) ^ sw) * 8;    // hi chunk b
  const float* pc2 = pre + col;            // c2[t*16+col] (global, L1)
  const float* pcw = pre + NCLUST + col;   // cw[...]

  float ss_0[4] = {0.f, 0.f, 0.f, 0.f}, ww_0[4] = {0.f, 0.f, 0.f, 0.f};
  float ss_1[4] = {0.f, 0.f, 0.f, 0.f}, ww_1[4] = {0.f, 0.f, 0.f, 0.f};

#pragma unroll 2
  for (int t = 0; t < 16; ++t) {
    const f16x8 bh0 = *(const f16x8*)(base0 + t * 2048);
    const f16x8 bh1 = *(const f16x8*)(base1 + t * 2048);
    const f16x8 bl0 = *(const f16x8*)(base0 + t * 2048 + 64);  // +8 chunks
    const f16x8 bl1 = *(const f16x8*)(base1 + t * 2048 + 64);
    const float c2c = pc2[t * 16];
    const float cwc = pcw[t * 16];

#define DO_RT(AH0, AL0, AH1, AL1, NHB, SS, WW) do {                         \
    f32x4 hh;                                                               \
    hh[0] = fmaf(-0.5f, c2c, NHB[0]);                                       \
    hh[1] = fmaf(-0.5f, c2c, NHB[1]);                                       \
    hh[2] = fmaf(-0.5f, c2c, NHB[2]);                                       \
    hh[3] = fmaf(-0.5f, c2c, NHB[3]);                                       \
    f32x4 hl = {0.f, 0.f, 0.f, 0.f};                                        \
    f32x4 lh = {0.f, 0.f, 0.f, 0.f};                                        \
    hh = __builtin_amdgcn_mfma_f32_16x16x32_f16(AH0, bh0, hh, 0, 0, 0);     \
    hl = __builtin_amdgcn_mfma_f32_16x16x32_f16(AH0, bl0, hl, 0, 0, 0);     \
    lh = __builtin_amdgcn_mfma_f32_16x16x32_f16(AL0, bh0, lh, 0, 0, 0);     \
    hh = __builtin_amdgcn_mfma_f32_16x16x32_f16(AH1, bh1, hh, 0, 0, 0);     \
    hl = __builtin_amdgcn_mfma_f32_16x16x32_f16(AH1, bl1, hl, 0, 0, 0);     \
    lh = __builtin_amdgcn_mfma_f32_16x16x32_f16(AL1, bh1, lh, 0, 0, 0);     \
    _Pragma("unroll") for (int r = 0; r < 4; ++r) {                         \
      const float m = hh[r] + (hl[r] + lh[r]);  /* dot - (h2+c2)/2 */       \
      const float dsc = sqrtf(fmaxf(m * KNEG2K, 0.f)); /* dist*log2e */     \
      const float e = exp2f(-dsc);              /* = exp(-dist) */          \
      SS[r] += e;                                                           \
      WW[r] = fmaf(e, cwc, WW[r]);                                          \
    }                                                                       \
  } while (0)

    DO_RT(ah0_0, al0_0, ah1_0, al1_0, nhb_0, ss_0, ww_0);
    DO_RT(ah0_1, al0_1, ah1_1, al1_1, nhb_1, ss_1, ww_1);
#undef DO_RT
  }

  // ---- reduce over the 16 cluster-lanes, store 32 tokens per wave ----
  const float b2v = b2[0];
#define STORE_RT(RTI, SS, WW) do {                                          \
    _Pragma("unroll") for (int r = 0; r < 4; ++r) {                         \
      float s = SS[r], w = WW[r];                                           \
      s += __shfl_xor(s, 1); w += __shfl_xor(w, 1);                         \
      s += __shfl_xor(s, 2); w += __shfl_xor(w, 2);                         \
      s += __shfl_xor(s, 4); w += __shfl_xor(w, 4);                         \
      s += __shfl_xor(s, 8); w += __shfl_xor(w, 8);                         \
      if (col == 0)                                                         \
        out[tokBase + (RTI) * 16 + g * 4 + r] = w / s * 0.125f + b2v;       \
    }                                                                       \
  } while (0)

  STORE_RT(0, ss_0, ww_0);
  STORE_RT(1, ss_1, ww_1);
#undef STORE_RT
}

extern "C" void kernel_launch(void* const* d_in, const int* in_sizes, int n_in,
                              void* d_out, int out_size, void* d_ws, size_t ws_size,
                              hipStream_t stream) {
  const float* x         = (const float*)d_in[0];
  const float* W_embed   = (const float*)d_in[1];
  const float* b_embed   = (const float*)d_in[2];
  const float* emb_table = (const float*)d_in[3];
  const float* centroids = (const float*)d_in[4];
  const float* W2        = (const float*)d_in[5];
  const float* b2        = (const float*)d_in[6];
  float* out = (float*)d_out;

  float* pre = (float*)d_ws;                              // 512 floats
  _Float16* cent_swz = (_Float16*)((char*)d_ws + 2048);   // 256*128 f16

  precompute_kernel<<<1, NCLUST, 0, stream>>>(centroids, W2, pre);
  split_kernel<<<(NCLUST * 16) / 256, 256, 0, stream>>>(centroids, cent_swz);
  const int tokPerBlk = 8 * 16 * RT;  // 256
  main_kernel<<<NTOK / tokPerBlk, BLK, 65536, stream>>>(
      x, W_embed, b_embed, emb_table, b2, pre, cent_swz, out);
}

// Round 12
// 60.125 us; speedup vs baseline: 1.4659x; 1.4659x over previous
//
#include <hip/hip_runtime.h>

// Problem constants
#define NTOK   (64 * 4096)   // B*S tokens
#define DDIM   64            // num_dim
#define NCLUST 256           // num_clusters
#define NFEAT  7             // continuous features
#define RT     2             // row-tiles of 16 tokens per wave
#define BLK    512           // threads per block (8 waves)
// tokens per block = 8 waves * RT*16 = 256 ; grid = 1024

typedef _Float16 f16x8 __attribute__((ext_vector_type(8)));
typedef float    f32x4 __attribute__((ext_vector_type(4)));

// -2 * (log2 e)^2 : folds softmax exp into exp2 and the -2 dot factor
#define KNEG2K (-4.1627379924399795f)

// ws layout: [0, 2048) float pre[512] = c2[256] ++ cw[256]
//            [2048, 2048+65536) _Float16 cent_swz[256*128]
// cent_swz row c: 16 chunks of 8 halves (16B):
//   chunk j in [0,8):  f16-hi of cent[c][j*8 .. j*8+8)
//   chunk j in [8,16): f16-lo of cent[c][(j-8)*8 .. +8)
// stored at chunk position (j ^ (c&7))  [XOR swizzle for ds_read_b128]

// ---- kernel 1a: per-cluster c2 / cw (verified R3/R5/R6, verbatim) ----
__global__ __launch_bounds__(NCLUST) void precompute_kernel(
    const float* __restrict__ centroids,
    const float* __restrict__ W2,
    float* __restrict__ pre) {
  const int c = threadIdx.x;
  const float4* cp = (const float4*)(centroids + c * DDIM);
  const float4* wp = (const float4*)W2;
  float c2a = 0.f, c2b = 0.f, cwa = 0.f, cwb = 0.f;
#pragma unroll
  for (int i = 0; i < DDIM / 4; i += 2) {
    float4 v0 = cp[i], v1 = cp[i + 1];
    float4 w0 = wp[i], w1 = wp[i + 1];
    c2a = fmaf(v0.x, v0.x, fmaf(v0.y, v0.y, fmaf(v0.z, v0.z, fmaf(v0.w, v0.w, c2a))));
    c2b = fmaf(v1.x, v1.x, fmaf(v1.y, v1.y, fmaf(v1.z, v1.z, fmaf(v1.w, v1.w, c2b))));
    cwa = fmaf(v0.x, w0.x, fmaf(v0.y, w0.y, fmaf(v0.z, w0.z, fmaf(v0.w, w0.w, cwa))));
    cwb = fmaf(v1.x, w1.x, fmaf(v1.y, w1.y, fmaf(v1.z, w1.z, fmaf(v1.w, w1.w, cwb))));
  }
  pre[c] = c2a + c2b;
  pre[NCLUST + c] = cwa + cwb;
}

// ---- kernel 1b: f16 hi/lo split -> XOR-swizzled chunk layout (verified R5/R6) ----
__global__ __launch_bounds__(256) void split_kernel(
    const float* __restrict__ centroids,
    _Float16* __restrict__ cent_swz) {
  const int tid = blockIdx.x * 256 + threadIdx.x;  // 0..4095
  const int c = tid >> 4;
  const int j = tid & 15;
  const int d0 = (j & 7) * 8;
  const bool lo = (j >= 8);
  f16x8 v;
#pragma unroll
  for (int i = 0; i < 8; ++i) {
    const float f = centroids[c * DDIM + d0 + i];
    const _Float16 h = (_Float16)f;
    v[i] = lo ? (_Float16)(f - (float)h) : h;
  }
  *(f16x8*)&cent_swz[c * 128 + (j ^ (c & 7)) * 8] = v;
}

// ---- kernel 2: fused main kernel ----
// 8 waves/block (512 thr), wave = 32 tokens (RT=2) x 256 clusters.
// R12: raw HW transcendentals. Without fast-math, sqrtf/exp2f lower to
// multi-op OCML sequences (R11: ~9.3k VALU instrs/wave, 70% VALUBusy at
// 88us). v_sqrt_f32 / v_exp_f32 / v_rcp_f32 are single ~1ULP trans ops --
// accuracy headroom is ~15x (absmax 6.1e-5 vs 9.4e-4 threshold).
__global__ __launch_bounds__(BLK, 2) void main_kernel(
    const float* __restrict__ x,
    const float* __restrict__ W_embed,
    const float* __restrict__ b_embed,
    const float* __restrict__ emb_table,
    const float* __restrict__ b2,
    const float* __restrict__ pre,
    const _Float16* __restrict__ cent_swz,
    float* __restrict__ out) {
  extern __shared__ _Float16 s_cent[];   // 256*128 halves = 65536 B exactly

  const int tid  = threadIdx.x;
  const int lane = tid & 63;
  const int wv   = tid >> 6;          // wave in block: 0..7
  const int col  = lane & 15;         // A-row (token) / B,C-col (cluster)
  const int g    = lane >> 4;         // k-group (0..3)
  const int tokBase = blockIdx.x * (8 * 16 * RT) + wv * (16 * RT);

  // ---- stage cent_swz (64KB) -> LDS ----
  {
    const float4* gsrc = (const float4*)cent_swz;   // 4096 float4
    float4* ldst = (float4*)s_cent;
#pragma unroll
    for (int i = 0; i < 8; ++i)
      ldst[tid + BLK * i] = gsrc[tid + BLK * i];
  }

  // ---- b_embed fragment (token-independent) ----
  const float4* br = (const float4*)b_embed;
  const float4 q0 = br[2 * g], q1 = br[2 * g + 1];
  const float4 q2 = br[8 + 2 * g], q3 = br[8 + 2 * g + 1];

  // ---- prologue: h[rt][0..7]=dims[g*8..+8), h[rt][8..15]=dims[32+g*8..+8) ----
  float h[RT][16];
  float xf[RT][NFEAT];
#pragma unroll
  for (int rt = 0; rt < RT; ++rt) {
    const int tok = tokBase + rt * 16 + col;
    const float4* xp = (const float4*)(x + (size_t)tok * 8);
    const float4 xa = xp[0], xb = xp[1];
    xf[rt][0] = xa.x; xf[rt][1] = xa.y; xf[rt][2] = xa.z; xf[rt][3] = xa.w;
    xf[rt][4] = xb.x; xf[rt][5] = xb.y; xf[rt][6] = xb.z;
    const int idx = (int)xb.w;
    const float4* er = (const float4*)(emb_table + (size_t)idx * DDIM);
    const float4 e0 = er[2 * g], e1 = er[2 * g + 1];
    const float4 e2 = er[8 + 2 * g], e3 = er[8 + 2 * g + 1];
    h[rt][0]  = e0.x + q0.x; h[rt][1]  = e0.y + q0.y;
    h[rt][2]  = e0.z + q0.z; h[rt][3]  = e0.w + q0.w;
    h[rt][4]  = e1.x + q1.x; h[rt][5]  = e1.y + q1.y;
    h[rt][6]  = e1.z + q1.z; h[rt][7]  = e1.w + q1.w;
    h[rt][8]  = e2.x + q2.x; h[rt][9]  = e2.y + q2.y;
    h[rt][10] = e2.z + q2.z; h[rt][11] = e2.w + q2.w;
    h[rt][12] = e3.x + q3.x; h[rt][13] = e3.y + q3.y;
    h[rt][14] = e3.z + q3.z; h[rt][15] = e3.w + q3.w;
  }
  // W_embed: f outer (W fragment loaded once), rt inner
#pragma unroll
  for (int f = 0; f < NFEAT; ++f) {
    const float4* wr = (const float4*)(W_embed + f * DDIM);
    const float4 w0 = wr[2 * g], w1 = wr[2 * g + 1];
    const float4 w2 = wr[8 + 2 * g], w3 = wr[8 + 2 * g + 1];
#pragma unroll
    for (int rt = 0; rt < RT; ++rt) {
      const float xv = xf[rt][f];
      h[rt][0]  = fmaf(xv, w0.x, h[rt][0]);  h[rt][1]  = fmaf(xv, w0.y, h[rt][1]);
      h[rt][2]  = fmaf(xv, w0.z, h[rt][2]);  h[rt][3]  = fmaf(xv, w0.w, h[rt][3]);
      h[rt][4]  = fmaf(xv, w1.x, h[rt][4]);  h[rt][5]  = fmaf(xv, w1.y, h[rt][5]);
      h[rt][6]  = fmaf(xv, w1.z, h[rt][6]);  h[rt][7]  = fmaf(xv, w1.w, h[rt][7]);
      h[rt][8]  = fmaf(xv, w2.x, h[rt][8]);  h[rt][9]  = fmaf(xv, w2.y, h[rt][9]);
      h[rt][10] = fmaf(xv, w2.z, h[rt][10]); h[rt][11] = fmaf(xv, w2.w, h[rt][11]);
      h[rt][12] = fmaf(xv, w3.x, h[rt][12]); h[rt][13] = fmaf(xv, w3.y, h[rt][13]);
      h[rt][14] = fmaf(xv, w3.z, h[rt][14]); h[rt][15] = fmaf(xv, w3.w, h[rt][15]);
    }
  }

  // ---- per-rt: h2 reduce (pre-scaled by -0.5) + f16 hi/lo split, NAMED frags ----
  f16x8 ah0_0, al0_0, ah1_0, al1_0; float nhb_0[4];
  f16x8 ah0_1, al0_1, ah1_1, al1_1; float nhb_1[4];

#define SPLIT_RT(RTI, AH0, AL0, AH1, AL1, NHB) do {                         \
    float ptl = 0.f;                                                        \
    _Pragma("unroll") for (int i = 0; i < 8; ++i) {                         \
      ptl = fmaf(h[RTI][i], h[RTI][i], ptl);                                \
      ptl = fmaf(h[RTI][8 + i], h[RTI][8 + i], ptl);                        \
    }                                                                       \
    ptl += __shfl_xor(ptl, 16);                                             \
    ptl += __shfl_xor(ptl, 32);                                             \
    ptl *= -0.5f;                                                           \
    _Pragma("unroll") for (int r = 0; r < 4; ++r)                           \
      NHB[r] = __shfl(ptl, g * 4 + r);                                      \
    _Pragma("unroll") for (int i = 0; i < 8; ++i) {                         \
      _Float16 t0 = (_Float16)h[RTI][i];                                    \
      AH0[i] = t0; AL0[i] = (_Float16)(h[RTI][i] - (float)t0);              \
      _Float16 t1 = (_Float16)h[RTI][8 + i];                                \
      AH1[i] = t1; AL1[i] = (_Float16)(h[RTI][8 + i] - (float)t1);          \
    }                                                                       \
  } while (0)

  SPLIT_RT(0, ah0_0, al0_0, ah1_0, al1_0, nhb_0);
  SPLIT_RT(1, ah0_1, al0_1, ah1_1, al1_1, nhb_1);
#undef SPLIT_RT

  __syncthreads();   // LDS stage complete

  // ---- loop-invariant LDS addressing (sw = (t*16+col)&7 = col&7) ----
  const int sw  = col & 7;
  const _Float16* base0 = s_cent + col * 128 + ((g) ^ sw) * 8;        // hi chunk a
  const _Float16* base1 = s_cent + col * 128 + ((4 + g) ^ sw) * 8;    // hi chunk b
  const float* pc2 = pre + col;            // c2[t*16+col] (global, L1)
  const float* pcw = pre + NCLUST + col;   // cw[...]

  float ss_0[4] = {0.f, 0.f, 0.f, 0.f}, ww_0[4] = {0.f, 0.f, 0.f, 0.f};
  float ss_1[4] = {0.f, 0.f, 0.f, 0.f}, ww_1[4] = {0.f, 0.f, 0.f, 0.f};

#pragma unroll 2
  for (int t = 0; t < 16; ++t) {
    const f16x8 bh0 = *(const f16x8*)(base0 + t * 2048);
    const f16x8 bh1 = *(const f16x8*)(base1 + t * 2048);
    const f16x8 bl0 = *(const f16x8*)(base0 + t * 2048 + 64);  // +8 chunks
    const f16x8 bl1 = *(const f16x8*)(base1 + t * 2048 + 64);
    const float c2c = pc2[t * 16];
    const float cwc = pcw[t * 16];

#define DO_RT(AH0, AL0, AH1, AL1, NHB, SS, WW) do {                         \
    f32x4 hh;                                                               \
    hh[0] = fmaf(-0.5f, c2c, NHB[0]);                                       \
    hh[1] = fmaf(-0.5f, c2c, NHB[1]);                                       \
    hh[2] = fmaf(-0.5f, c2c, NHB[2]);                                       \
    hh[3] = fmaf(-0.5f, c2c, NHB[3]);                                       \
    f32x4 hl = {0.f, 0.f, 0.f, 0.f};                                        \
    f32x4 lh = {0.f, 0.f, 0.f, 0.f};                                        \
    hh = __builtin_amdgcn_mfma_f32_16x16x32_f16(AH0, bh0, hh, 0, 0, 0);     \
    hl = __builtin_amdgcn_mfma_f32_16x16x32_f16(AH0, bl0, hl, 0, 0, 0);     \
    lh = __builtin_amdgcn_mfma_f32_16x16x32_f16(AL0, bh0, lh, 0, 0, 0);     \
    hh = __builtin_amdgcn_mfma_f32_16x16x32_f16(AH1, bh1, hh, 0, 0, 0);     \
    hl = __builtin_amdgcn_mfma_f32_16x16x32_f16(AH1, bl1, hl, 0, 0, 0);     \
    lh = __builtin_amdgcn_mfma_f32_16x16x32_f16(AL1, bh1, lh, 0, 0, 0);     \
    _Pragma("unroll") for (int r = 0; r < 4; ++r) {                         \
      const float m = hh[r] + (hl[r] + lh[r]);  /* dot - (h2+c2)/2 */       \
      const float d2s = fmaxf(m * KNEG2K, 0.f); /* (dist*log2e)^2 */        \
      const float dsc = __builtin_amdgcn_sqrtf(d2s);   /* v_sqrt_f32 */     \
      const float e = __builtin_amdgcn_exp2f(-dsc);    /* v_exp_f32 */      \
      SS[r] += e;                                                           \
      WW[r] = fmaf(e, cwc, WW[r]);                                          \
    }                                                                       \
  } while (0)

    DO_RT(ah0_0, al0_0, ah1_0, al1_0, nhb_0, ss_0, ww_0);
    DO_RT(ah0_1, al0_1, ah1_1, al1_1, nhb_1, ss_1, ww_1);
#undef DO_RT
  }

  // ---- reduce over the 16 cluster-lanes, store 32 tokens per wave ----
  const float b2v = b2[0];
#define STORE_RT(RTI, SS, WW) do {                                          \
    _Pragma("unroll") for (int r = 0; r < 4; ++r) {                         \
      float s = SS[r], w = WW[r];                                           \
      s += __shfl_xor(s, 1); w += __shfl_xor(w, 1);                         \
      s += __shfl_xor(s, 2); w += __shfl_xor(w, 2);                         \
      s += __shfl_xor(s, 4); w += __shfl_xor(w, 4);                         \
      s += __shfl_xor(s, 8); w += __shfl_xor(w, 8);                         \
      if (col == 0)                                                         \
        out[tokBase + (RTI) * 16 + g * 4 + r] =                             \
            w * __builtin_amdgcn_rcpf(s) * 0.125f + b2v;                    \
    }                                                                       \
  } while (0)

  STORE_RT(0, ss_0, ww_0);
  STORE_RT(1, ss_1, ww_1);
#undef STORE_RT
}

extern "C" void kernel_launch(void* const* d_in, const int* in_sizes, int n_in,
                              void* d_out, int out_size, void* d_ws, size_t ws_size,
                              hipStream_t stream) {
  const float* x         = (const float*)d_in[0];
  const float* W_embed   = (const float*)d_in[1];
  const float* b_embed   = (const float*)d_in[2];
  const float* emb_table = (const float*)d_in[3];
  const float* centroids = (const float*)d_in[4];
  const float* W2        = (const float*)d_in[5];
  const float* b2        = (const float*)d_in[6];
  float* out = (float*)d_out;

  float* pre = (float*)d_ws;                              // 512 floats
  _Float16* cent_swz = (_Float16*)((char*)d_ws + 2048);   // 256*128 f16

  precompute_kernel<<<1, NCLUST, 0, stream>>>(centroids, W2, pre);
  split_kernel<<<(NCLUST * 16) / 256, 256, 0, stream>>>(centroids, cent_swz);
  const int tokPerBlk = 8 * 16 * RT;  // 256
  main_kernel<<<NTOK / tokPerBlk, BLK, 65536, stream>>>(
      x, W_embed, b_embed, emb_table, b2, pre, cent_swz, out);
}

// Round 13
// 55.418 us; speedup vs baseline: 1.5904x; 1.0849x over previous
//
#include <hip/hip_runtime.h>

// Problem constants
#define NTOK   (64 * 4096)   // B*S tokens
#define DDIM   64            // num_dim
#define NCLUST 256           // num_clusters
#define NFEAT  7             // continuous features
#define RT     2             // row-tiles of 16 tokens per wave
#define BLK    512           // threads per block (8 waves)
// tokens per block = 8 waves * RT*16 = 256 ; grid = 1024

typedef _Float16 f16x8 __attribute__((ext_vector_type(8)));
typedef float    f32x4 __attribute__((ext_vector_type(4)));

// -2 * (log2 e)^2 : folds softmax exp into exp2 and the -2 dot factor
#define KNEG2K (-4.1627379924399795f)

// ws layout: [0, 2048) float pre[512] = c2[256] ++ cw[256]
//            [2048, 2048+32768) _Float16 cent_hswz[256*64]   (f16-hi ONLY)
// cent_hswz row c: 8 chunks of 8 halves (16B); chunk j = f16(cent[c][j*8..+8))
// stored at chunk position (j ^ (c&7))  [XOR swizzle for ds_read_b128]
// B-lo dropped: A-side hi+lo against B-hi gives dot = h * c_hi exactly-ish;
// c's f16 rounding adds ~3e-4 on dist -> ~1e-4 on output (threshold 9.4e-4).

// ---- kernel 1a: per-cluster c2 / cw (verified R3..R12, verbatim) ----
__global__ __launch_bounds__(NCLUST) void precompute_kernel(
    const float* __restrict__ centroids,
    const float* __restrict__ W2,
    float* __restrict__ pre) {
  const int c = threadIdx.x;
  const float4* cp = (const float4*)(centroids + c * DDIM);
  const float4* wp = (const float4*)W2;
  float c2a = 0.f, c2b = 0.f, cwa = 0.f, cwb = 0.f;
#pragma unroll
  for (int i = 0; i < DDIM / 4; i += 2) {
    float4 v0 = cp[i], v1 = cp[i + 1];
    float4 w0 = wp[i], w1 = wp[i + 1];
    c2a = fmaf(v0.x, v0.x, fmaf(v0.y, v0.y, fmaf(v0.z, v0.z, fmaf(v0.w, v0.w, c2a))));
    c2b = fmaf(v1.x, v1.x, fmaf(v1.y, v1.y, fmaf(v1.z, v1.z, fmaf(v1.w, v1.w, c2b))));
    cwa = fmaf(v0.x, w0.x, fmaf(v0.y, w0.y, fmaf(v0.z, w0.z, fmaf(v0.w, w0.w, cwa))));
    cwb = fmaf(v1.x, w1.x, fmaf(v1.y, w1.y, fmaf(v1.z, w1.z, fmaf(v1.w, w1.w, cwb))));
  }
  pre[c] = c2a + c2b;
  pre[NCLUST + c] = cwa + cwb;
}

// ---- kernel 1b: f16-hi split -> XOR-swizzled chunk layout (32KB table) ----
__global__ __launch_bounds__(256) void split_kernel(
    const float* __restrict__ centroids,
    _Float16* __restrict__ cent_hswz) {
  const int tid = blockIdx.x * 256 + threadIdx.x;  // 0..2047
  const int c = tid >> 3;
  const int j = tid & 7;
  const int d0 = j * 8;
  f16x8 v;
#pragma unroll
  for (int i = 0; i < 8; ++i)
    v[i] = (_Float16)centroids[c * DDIM + d0 + i];
  *(f16x8*)&cent_hswz[c * 64 + (j ^ (c & 7)) * 8] = v;
}

// ---- kernel 2: fused main kernel ----
// 8 waves/block (512 thr), wave = 32 tokens (RT=2) x 256 clusters.
// LDS = 32768 B (f16-hi table) -> 2 blocks/CU co-resident (16 waves/CU,
// VGPR-capped at 68 regs). 4 MFMA per rt*tile: (ah0,ah1,al0,al1) x bh.
__global__ __launch_bounds__(BLK, 2) void main_kernel(
    const float* __restrict__ x,
    const float* __restrict__ W_embed,
    const float* __restrict__ b_embed,
    const float* __restrict__ emb_table,
    const float* __restrict__ b2,
    const float* __restrict__ pre,
    const _Float16* __restrict__ cent_hswz,
    float* __restrict__ out) {
  extern __shared__ _Float16 s_cent[];   // 256*64 halves = 32768 B

  const int tid  = threadIdx.x;
  const int lane = tid & 63;
  const int wv   = tid >> 6;          // wave in block: 0..7
  const int col  = lane & 15;         // A-row (token) / B,C-col (cluster)
  const int g    = lane >> 4;         // k-group (0..3)
  const int tokBase = blockIdx.x * (8 * 16 * RT) + wv * (16 * RT);

  // ---- stage cent_hswz (32KB) -> LDS ----
  {
    const float4* gsrc = (const float4*)cent_hswz;   // 2048 float4
    float4* ldst = (float4*)s_cent;
#pragma unroll
    for (int i = 0; i < 4; ++i)
      ldst[tid + BLK * i] = gsrc[tid + BLK * i];
  }

  // ---- b_embed fragment (token-independent) ----
  const float4* br = (const float4*)b_embed;
  const float4 q0 = br[2 * g], q1 = br[2 * g + 1];
  const float4 q2 = br[8 + 2 * g], q3 = br[8 + 2 * g + 1];

  // ---- prologue: h[rt][0..7]=dims[g*8..+8), h[rt][8..15]=dims[32+g*8..+8) ----
  float h[RT][16];
  float xf[RT][NFEAT];
#pragma unroll
  for (int rt = 0; rt < RT; ++rt) {
    const int tok = tokBase + rt * 16 + col;
    const float4* xp = (const float4*)(x + (size_t)tok * 8);
    const float4 xa = xp[0], xb = xp[1];
    xf[rt][0] = xa.x; xf[rt][1] = xa.y; xf[rt][2] = xa.z; xf[rt][3] = xa.w;
    xf[rt][4] = xb.x; xf[rt][5] = xb.y; xf[rt][6] = xb.z;
    const int idx = (int)xb.w;
    const float4* er = (const float4*)(emb_table + (size_t)idx * DDIM);
    const float4 e0 = er[2 * g], e1 = er[2 * g + 1];
    const float4 e2 = er[8 + 2 * g], e3 = er[8 + 2 * g + 1];
    h[rt][0]  = e0.x + q0.x; h[rt][1]  = e0.y + q0.y;
    h[rt][2]  = e0.z + q0.z; h[rt][3]  = e0.w + q0.w;
    h[rt][4]  = e1.x + q1.x; h[rt][5]  = e1.y + q1.y;
    h[rt][6]  = e1.z + q1.z; h[rt][7]  = e1.w + q1.w;
    h[rt][8]  = e2.x + q2.x; h[rt][9]  = e2.y + q2.y;
    h[rt][10] = e2.z + q2.z; h[rt][11] = e2.w + q2.w;
    h[rt][12] = e3.x + q3.x; h[rt][13] = e3.y + q3.y;
    h[rt][14] = e3.z + q3.z; h[rt][15] = e3.w + q3.w;
  }
  // W_embed: f outer (W fragment loaded once), rt inner
#pragma unroll
  for (int f = 0; f < NFEAT; ++f) {
    const float4* wr = (const float4*)(W_embed + f * DDIM);
    const float4 w0 = wr[2 * g], w1 = wr[2 * g + 1];
    const float4 w2 = wr[8 + 2 * g], w3 = wr[8 + 2 * g + 1];
#pragma unroll
    for (int rt = 0; rt < RT; ++rt) {
      const float xv = xf[rt][f];
      h[rt][0]  = fmaf(xv, w0.x, h[rt][0]);  h[rt][1]  = fmaf(xv, w0.y, h[rt][1]);
      h[rt][2]  = fmaf(xv, w0.z, h[rt][2]);  h[rt][3]  = fmaf(xv, w0.w, h[rt][3]);
      h[rt][4]  = fmaf(xv, w1.x, h[rt][4]);  h[rt][5]  = fmaf(xv, w1.y, h[rt][5]);
      h[rt][6]  = fmaf(xv, w1.z, h[rt][6]);  h[rt][7]  = fmaf(xv, w1.w, h[rt][7]);
      h[rt][8]  = fmaf(xv, w2.x, h[rt][8]);  h[rt][9]  = fmaf(xv, w2.y, h[rt][9]);
      h[rt][10] = fmaf(xv, w2.z, h[rt][10]); h[rt][11] = fmaf(xv, w2.w, h[rt][11]);
      h[rt][12] = fmaf(xv, w3.x, h[rt][12]); h[rt][13] = fmaf(xv, w3.y, h[rt][13]);
      h[rt][14] = fmaf(xv, w3.z, h[rt][14]); h[rt][15] = fmaf(xv, w3.w, h[rt][15]);
    }
  }

  // ---- per-rt: h2 reduce (pre-scaled by -0.5) + f16 hi/lo split, NAMED frags ----
  f16x8 ah0_0, al0_0, ah1_0, al1_0; float nhb_0[4];
  f16x8 ah0_1, al0_1, ah1_1, al1_1; float nhb_1[4];

#define SPLIT_RT(RTI, AH0, AL0, AH1, AL1, NHB) do {                         \
    float ptl = 0.f;                                                        \
    _Pragma("unroll") for (int i = 0; i < 8; ++i) {                         \
      ptl = fmaf(h[RTI][i], h[RTI][i], ptl);                                \
      ptl = fmaf(h[RTI][8 + i], h[RTI][8 + i], ptl);                        \
    }                                                                       \
    ptl += __shfl_xor(ptl, 16);                                             \
    ptl += __shfl_xor(ptl, 32);                                             \
    ptl *= -0.5f;                                                           \
    _Pragma("unroll") for (int r = 0; r < 4; ++r)                           \
      NHB[r] = __shfl(ptl, g * 4 + r);                                      \
    _Pragma("unroll") for (int i = 0; i < 8; ++i) {                         \
      _Float16 t0 = (_Float16)h[RTI][i];                                    \
      AH0[i] = t0; AL0[i] = (_Float16)(h[RTI][i] - (float)t0);              \
      _Float16 t1 = (_Float16)h[RTI][8 + i];                                \
      AH1[i] = t1; AL1[i] = (_Float16)(h[RTI][8 + i] - (float)t1);          \
    }                                                                       \
  } while (0)

  SPLIT_RT(0, ah0_0, al0_0, ah1_0, al1_0, nhb_0);
  SPLIT_RT(1, ah0_1, al0_1, ah1_1, al1_1, nhb_1);
#undef SPLIT_RT

  __syncthreads();   // LDS stage complete

  // ---- loop-invariant LDS addressing (sw = (t*16+col)&7 = col&7) ----
  const int sw  = col & 7;
  const _Float16* base0 = s_cent + col * 64 + ((g) ^ sw) * 8;       // chunk a
  const _Float16* base1 = s_cent + col * 64 + ((4 + g) ^ sw) * 8;   // chunk b
  const float* pc2 = pre + col;            // c2[t*16+col] (global, L1)
  const float* pcw = pre + NCLUST + col;   // cw[...]

  float ss_0[4] = {0.f, 0.f, 0.f, 0.f}, ww_0[4] = {0.f, 0.f, 0.f, 0.f};
  float ss_1[4] = {0.f, 0.f, 0.f, 0.f}, ww_1[4] = {0.f, 0.f, 0.f, 0.f};

#pragma unroll 2
  for (int t = 0; t < 16; ++t) {
    const f16x8 bh0 = *(const f16x8*)(base0 + t * 1024);   // 16 clusters*64 halves
    const f16x8 bh1 = *(const f16x8*)(base1 + t * 1024);
    const float c2c = pc2[t * 16];
    const float cwc = pcw[t * 16];

#define DO_RT(AH0, AL0, AH1, AL1, NHB, SS, WW) do {                         \
    f32x4 hh;                                                               \
    hh[0] = fmaf(-0.5f, c2c, NHB[0]);                                       \
    hh[1] = fmaf(-0.5f, c2c, NHB[1]);                                       \
    hh[2] = fmaf(-0.5f, c2c, NHB[2]);                                       \
    hh[3] = fmaf(-0.5f, c2c, NHB[3]);                                       \
    f32x4 lh = {0.f, 0.f, 0.f, 0.f};                                        \
    hh = __builtin_amdgcn_mfma_f32_16x16x32_f16(AH0, bh0, hh, 0, 0, 0);     \
    lh = __builtin_amdgcn_mfma_f32_16x16x32_f16(AL0, bh0, lh, 0, 0, 0);     \
    hh = __builtin_amdgcn_mfma_f32_16x16x32_f16(AH1, bh1, hh, 0, 0, 0);     \
    lh = __builtin_amdgcn_mfma_f32_16x16x32_f16(AL1, bh1, lh, 0, 0, 0);     \
    _Pragma("unroll") for (int r = 0; r < 4; ++r) {                         \
      const float m = hh[r] + lh[r];            /* h.c_hi - (h2+c2)/2 */    \
      const float d2s = fmaxf(m * KNEG2K, 0.f); /* (dist*log2e)^2 */        \
      const float dsc = __builtin_amdgcn_sqrtf(d2s);   /* v_sqrt_f32 */     \
      const float e = __builtin_amdgcn_exp2f(-dsc);    /* v_exp_f32 */      \
      SS[r] += e;                                                           \
      WW[r] = fmaf(e, cwc, WW[r]);                                          \
    }                                                                       \
  } while (0)

    DO_RT(ah0_0, al0_0, ah1_0, al1_0, nhb_0, ss_0, ww_0);
    DO_RT(ah0_1, al0_1, ah1_1, al1_1, nhb_1, ss_1, ww_1);
#undef DO_RT
  }

  // ---- reduce over the 16 cluster-lanes, store 32 tokens per wave ----
  const float b2v = b2[0];
#define STORE_RT(RTI, SS, WW) do {                                          \
    _Pragma("unroll") for (int r = 0; r < 4; ++r) {                         \
      float s = SS[r], w = WW[r];                                           \
      s += __shfl_xor(s, 1); w += __shfl_xor(w, 1);                         \
      s += __shfl_xor(s, 2); w += __shfl_xor(w, 2);                         \
      s += __shfl_xor(s, 4); w += __shfl_xor(w, 4);                         \
      s += __shfl_xor(s, 8); w += __shfl_xor(w, 8);                         \
      if (col == 0)                                                         \
        out[tokBase + (RTI) * 16 + g * 4 + r] =                             \
            w * __builtin_amdgcn_rcpf(s) * 0.125f + b2v;                    \
    }                                                                       \
  } while (0)

  STORE_RT(0, ss_0, ww_0);
  STORE_RT(1, ss_1, ww_1);
#undef STORE_RT
}

extern "C" void kernel_launch(void* const* d_in, const int* in_sizes, int n_in,
                              void* d_out, int out_size, void* d_ws, size_t ws_size,
                              hipStream_t stream) {
  const float* x         = (const float*)d_in[0];
  const float* W_embed   = (const float*)d_in[1];
  const float* b_embed   = (const float*)d_in[2];
  const float* emb_table = (const float*)d_in[3];
  const float* centroids = (const float*)d_in[4];
  const float* W2        = (const float*)d_in[5];
  const float* b2        = (const float*)d_in[6];
  float* out = (float*)d_out;

  float* pre = (float*)d_ws;                               // 512 floats
  _Float16* cent_hswz = (_Float16*)((char*)d_ws + 2048);   // 256*64 f16

  precompute_kernel<<<1, NCLUST, 0, stream>>>(centroids, W2, pre);
  split_kernel<<<(NCLUST * 8) / 256, 256, 0, stream>>>(centroids, cent_hswz);
  const int tokPerBlk = 8 * 16 * RT;  // 256
  main_kernel<<<NTOK / tokPerBlk, BLK, 32768, stream>>>(
      x, W_embed, b_embed, emb_table, b2, pre, cent_hswz, out);
}

// Round 14
// 54.236 us; speedup vs baseline: 1.6251x; 1.0218x over previous
//
#include <hip/hip_runtime.h>

// Problem constants
#define NTOK   (64 * 4096)   // B*S tokens
#define DDIM   64            // num_dim
#define NCLUST 256           // num_clusters
#define NFEAT  7             // continuous features
#define RT     4             // row-tiles of 16 tokens per wave
#define BLK    256           // threads per block (4 waves)
// tokens per block = 4 waves * RT*16 = 256 ; grid = 1024

typedef _Float16 f16x8 __attribute__((ext_vector_type(8)));
typedef float    f32x4 __attribute__((ext_vector_type(4)));

// -2 * (log2 e)^2 : folds softmax exp into exp2 and the -2 dot factor
#define KNEG2K (-4.1627379924399795f)

// ws layout: [0, 2048) float pre[512] = c2[256] ++ cw[256]
//            [2048, 2048+32768) _Float16 cent_hswz[256*64]   (f16-hi ONLY)
// cent_hswz row c: 8 chunks of 8 halves (16B); chunk j = f16(cent[c][j*8..+8))
// stored at chunk position (j ^ (c&7))  [XOR swizzle; measured 0 conflicts R13]

// ---- kernel 1a: per-cluster c2 / cw (verified R3..R13, verbatim) ----
__global__ __launch_bounds__(NCLUST) void precompute_kernel(
    const float* __restrict__ centroids,
    const float* __restrict__ W2,
    float* __restrict__ pre) {
  const int c = threadIdx.x;
  const float4* cp = (const float4*)(centroids + c * DDIM);
  const float4* wp = (const float4*)W2;
  float c2a = 0.f, c2b = 0.f, cwa = 0.f, cwb = 0.f;
#pragma unroll
  for (int i = 0; i < DDIM / 4; i += 2) {
    float4 v0 = cp[i], v1 = cp[i + 1];
    float4 w0 = wp[i], w1 = wp[i + 1];
    c2a = fmaf(v0.x, v0.x, fmaf(v0.y, v0.y, fmaf(v0.z, v0.z, fmaf(v0.w, v0.w, c2a))));
    c2b = fmaf(v1.x, v1.x, fmaf(v1.y, v1.y, fmaf(v1.z, v1.z, fmaf(v1.w, v1.w, c2b))));
    cwa = fmaf(v0.x, w0.x, fmaf(v0.y, w0.y, fmaf(v0.z, w0.z, fmaf(v0.w, w0.w, cwa))));
    cwb = fmaf(v1.x, w1.x, fmaf(v1.y, w1.y, fmaf(v1.z, w1.z, fmaf(v1.w, w1.w, cwb))));
  }
  pre[c] = c2a + c2b;
  pre[NCLUST + c] = cwa + cwb;
}

// ---- kernel 1b: f16-hi split -> XOR-swizzled chunk layout (verified R13) ----
__global__ __launch_bounds__(256) void split_kernel(
    const float* __restrict__ centroids,
    _Float16* __restrict__ cent_hswz) {
  const int tid = blockIdx.x * 256 + threadIdx.x;  // 0..2047
  const int c = tid >> 3;
  const int j = tid & 7;
  const int d0 = j * 8;
  f16x8 v;
#pragma unroll
  for (int i = 0; i < 8; ++i)
    v[i] = (_Float16)centroids[c * DDIM + d0 + i];
  *(f16x8*)&cent_hswz[c * 64 + (j ^ (c & 7)) * 8] = v;
}

// ---- kernel 2: fused main kernel ----
// 4 waves/block (256 thr), wave = 64 tokens (RT=4) x 256 clusters.
// R14: RT=4 for 4 independent epilogue streams/wave (R13 was latency-bound:
// VALU 41%, MFMA 12%, occupancy pinned ~22% for 512-thr blocks). 256-thr
// blocks + 32KB LDS -> more blocks/CU co-schedulable. All R12/R13 wins kept:
// hi-only table, raw v_sqrt/v_exp/v_rcp, imm-offset LDS, c2 folded into C-in.
__global__ __launch_bounds__(BLK, 2) void main_kernel(
    const float* __restrict__ x,
    const float* __restrict__ W_embed,
    const float* __restrict__ b_embed,
    const float* __restrict__ emb_table,
    const float* __restrict__ b2,
    const float* __restrict__ pre,
    const _Float16* __restrict__ cent_hswz,
    float* __restrict__ out) {
  extern __shared__ _Float16 s_cent[];   // 256*64 halves = 32768 B

  const int tid  = threadIdx.x;
  const int lane = tid & 63;
  const int wv   = tid >> 6;          // wave in block: 0..3
  const int col  = lane & 15;         // A-row (token) / B,C-col (cluster)
  const int g    = lane >> 4;         // k-group (0..3)
  const int tokBase = blockIdx.x * (4 * 16 * RT) + wv * (16 * RT);

  // ---- stage cent_hswz (32KB) -> LDS ----
  {
    const float4* gsrc = (const float4*)cent_hswz;   // 2048 float4
    float4* ldst = (float4*)s_cent;
#pragma unroll
    for (int i = 0; i < 8; ++i)
      ldst[tid + BLK * i] = gsrc[tid + BLK * i];
  }

  // ---- b_embed fragment (token-independent) ----
  const float4* br = (const float4*)b_embed;
  const float4 q0 = br[2 * g], q1 = br[2 * g + 1];
  const float4 q2 = br[8 + 2 * g], q3 = br[8 + 2 * g + 1];

  // ---- prologue: h[rt][0..7]=dims[g*8..+8), h[rt][8..15]=dims[32+g*8..+8) ----
  float h[RT][16];
  float xf[RT][NFEAT];
#pragma unroll
  for (int rt = 0; rt < RT; ++rt) {
    const int tok = tokBase + rt * 16 + col;
    const float4* xp = (const float4*)(x + (size_t)tok * 8);
    const float4 xa = xp[0], xb = xp[1];
    xf[rt][0] = xa.x; xf[rt][1] = xa.y; xf[rt][2] = xa.z; xf[rt][3] = xa.w;
    xf[rt][4] = xb.x; xf[rt][5] = xb.y; xf[rt][6] = xb.z;
    const int idx = (int)xb.w;
    const float4* er = (const float4*)(emb_table + (size_t)idx * DDIM);
    const float4 e0 = er[2 * g], e1 = er[2 * g + 1];
    const float4 e2 = er[8 + 2 * g], e3 = er[8 + 2 * g + 1];
    h[rt][0]  = e0.x + q0.x; h[rt][1]  = e0.y + q0.y;
    h[rt][2]  = e0.z + q0.z; h[rt][3]  = e0.w + q0.w;
    h[rt][4]  = e1.x + q1.x; h[rt][5]  = e1.y + q1.y;
    h[rt][6]  = e1.z + q1.z; h[rt][7]  = e1.w + q1.w;
    h[rt][8]  = e2.x + q2.x; h[rt][9]  = e2.y + q2.y;
    h[rt][10] = e2.z + q2.z; h[rt][11] = e2.w + q2.w;
    h[rt][12] = e3.x + q3.x; h[rt][13] = e3.y + q3.y;
    h[rt][14] = e3.z + q3.z; h[rt][15] = e3.w + q3.w;
  }
  // W_embed: f outer (W fragment loaded once), rt inner (reused 4x)
#pragma unroll
  for (int f = 0; f < NFEAT; ++f) {
    const float4* wr = (const float4*)(W_embed + f * DDIM);
    const float4 w0 = wr[2 * g], w1 = wr[2 * g + 1];
    const float4 w2 = wr[8 + 2 * g], w3 = wr[8 + 2 * g + 1];
#pragma unroll
    for (int rt = 0; rt < RT; ++rt) {
      const float xv = xf[rt][f];
      h[rt][0]  = fmaf(xv, w0.x, h[rt][0]);  h[rt][1]  = fmaf(xv, w0.y, h[rt][1]);
      h[rt][2]  = fmaf(xv, w0.z, h[rt][2]);  h[rt][3]  = fmaf(xv, w0.w, h[rt][3]);
      h[rt][4]  = fmaf(xv, w1.x, h[rt][4]);  h[rt][5]  = fmaf(xv, w1.y, h[rt][5]);
      h[rt][6]  = fmaf(xv, w1.z, h[rt][6]);  h[rt][7]  = fmaf(xv, w1.w, h[rt][7]);
      h[rt][8]  = fmaf(xv, w2.x, h[rt][8]);  h[rt][9]  = fmaf(xv, w2.y, h[rt][9]);
      h[rt][10] = fmaf(xv, w2.z, h[rt][10]); h[rt][11] = fmaf(xv, w2.w, h[rt][11]);
      h[rt][12] = fmaf(xv, w3.x, h[rt][12]); h[rt][13] = fmaf(xv, w3.y, h[rt][13]);
      h[rt][14] = fmaf(xv, w3.z, h[rt][14]); h[rt][15] = fmaf(xv, w3.w, h[rt][15]);
    }
  }

  // ---- per-rt: h2 reduce (pre-scaled by -0.5) + f16 hi/lo split, NAMED frags ----
  f16x8 ah0_0, al0_0, ah1_0, al1_0; float nhb_0[4];
  f16x8 ah0_1, al0_1, ah1_1, al1_1; float nhb_1[4];
  f16x8 ah0_2, al0_2, ah1_2, al1_2; float nhb_2[4];
  f16x8 ah0_3, al0_3, ah1_3, al1_3; float nhb_3[4];

#define SPLIT_RT(RTI, AH0, AL0, AH1, AL1, NHB) do {                         \
    float ptl = 0.f;                                                        \
    _Pragma("unroll") for (int i = 0; i < 8; ++i) {                         \
      ptl = fmaf(h[RTI][i], h[RTI][i], ptl);                                \
      ptl = fmaf(h[RTI][8 + i], h[RTI][8 + i], ptl);                        \
    }                                                                       \
    ptl += __shfl_xor(ptl, 16);                                             \
    ptl += __shfl_xor(ptl, 32);                                             \
    ptl *= -0.5f;                                                           \
    _Pragma("unroll") for (int r = 0; r < 4; ++r)                           \
      NHB[r] = __shfl(ptl, g * 4 + r);                                      \
    _Pragma("unroll") for (int i = 0; i < 8; ++i) {                         \
      _Float16 t0 = (_Float16)h[RTI][i];                                    \
      AH0[i] = t0; AL0[i] = (_Float16)(h[RTI][i] - (float)t0);              \
      _Float16 t1 = (_Float16)h[RTI][8 + i];                                \
      AH1[i] = t1; AL1[i] = (_Float16)(h[RTI][8 + i] - (float)t1);          \
    }                                                                       \
  } while (0)

  SPLIT_RT(0, ah0_0, al0_0, ah1_0, al1_0, nhb_0);
  SPLIT_RT(1, ah0_1, al0_1, ah1_1, al1_1, nhb_1);
  SPLIT_RT(2, ah0_2, al0_2, ah1_2, al1_2, nhb_2);
  SPLIT_RT(3, ah0_3, al0_3, ah1_3, al1_3, nhb_3);
#undef SPLIT_RT

  __syncthreads();   // LDS stage complete

  // ---- loop-invariant LDS addressing (sw = (t*16+col)&7 = col&7) ----
  const int sw  = col & 7;
  const _Float16* base0 = s_cent + col * 64 + ((g) ^ sw) * 8;       // chunk a
  const _Float16* base1 = s_cent + col * 64 + ((4 + g) ^ sw) * 8;   // chunk b
  const float* pc2 = pre + col;            // c2[t*16+col] (global, L1)
  const float* pcw = pre + NCLUST + col;   // cw[...]

  float ss_0[4] = {0.f, 0.f, 0.f, 0.f}, ww_0[4] = {0.f, 0.f, 0.f, 0.f};
  float ss_1[4] = {0.f, 0.f, 0.f, 0.f}, ww_1[4] = {0.f, 0.f, 0.f, 0.f};
  float ss_2[4] = {0.f, 0.f, 0.f, 0.f}, ww_2[4] = {0.f, 0.f, 0.f, 0.f};
  float ss_3[4] = {0.f, 0.f, 0.f, 0.f}, ww_3[4] = {0.f, 0.f, 0.f, 0.f};

#pragma unroll 2
  for (int t = 0; t < 16; ++t) {
    const f16x8 bh0 = *(const f16x8*)(base0 + t * 1024);   // 16 clusters*64 halves
    const f16x8 bh1 = *(const f16x8*)(base1 + t * 1024);
    const float c2c = pc2[t * 16];
    const float cwc = pcw[t * 16];

#define DO_RT(AH0, AL0, AH1, AL1, NHB, SS, WW) do {                         \
    f32x4 hh;                                                               \
    hh[0] = fmaf(-0.5f, c2c, NHB[0]);                                       \
    hh[1] = fmaf(-0.5f, c2c, NHB[1]);                                       \
    hh[2] = fmaf(-0.5f, c2c, NHB[2]);                                       \
    hh[3] = fmaf(-0.5f, c2c, NHB[3]);                                       \
    f32x4 lh = {0.f, 0.f, 0.f, 0.f};                                        \
    hh = __builtin_amdgcn_mfma_f32_16x16x32_f16(AH0, bh0, hh, 0, 0, 0);     \
    lh = __builtin_amdgcn_mfma_f32_16x16x32_f16(AL0, bh0, lh, 0, 0, 0);     \
    hh = __builtin_amdgcn_mfma_f32_16x16x32_f16(AH1, bh1, hh, 0, 0, 0);     \
    lh = __builtin_amdgcn_mfma_f32_16x16x32_f16(AL1, bh1, lh, 0, 0, 0);     \
    _Pragma("unroll") for (int r = 0; r < 4; ++r) {                         \
      const float m = hh[r] + lh[r];            /* h.c_hi - (h2+c2)/2 */    \
      const float d2s = fmaxf(m * KNEG2K, 0.f); /* (dist*log2e)^2 */        \
      const float dsc = __builtin_amdgcn_sqrtf(d2s);   /* v_sqrt_f32 */     \
      const float e = __builtin_amdgcn_exp2f(-dsc);    /* v_exp_f32 */      \
      SS[r] += e;                                                           \
      WW[r] = fmaf(e, cwc, WW[r]);                                          \
    }                                                                       \
  } while (0)

    DO_RT(ah0_0, al0_0, ah1_0, al1_0, nhb_0, ss_0, ww_0);
    DO_RT(ah0_1, al0_1, ah1_1, al1_1, nhb_1, ss_1, ww_1);
    DO_RT(ah0_2, al0_2, ah1_2, al1_2, nhb_2, ss_2, ww_2);
    DO_RT(ah0_3, al0_3, ah1_3, al1_3, nhb_3, ss_3, ww_3);
#undef DO_RT
  }

  // ---- reduce over the 16 cluster-lanes, store 64 tokens per wave ----
  const float b2v = b2[0];
#define STORE_RT(RTI, SS, WW) do {                                          \
    _Pragma("unroll") for (int r = 0; r < 4; ++r) {                         \
      float s = SS[r], w = WW[r];                                           \
      s += __shfl_xor(s, 1); w += __shfl_xor(w, 1);                         \
      s += __shfl_xor(s, 2); w += __shfl_xor(w, 2);                         \
      s += __shfl_xor(s, 4); w += __shfl_xor(w, 4);                         \
      s += __shfl_xor(s, 8); w += __shfl_xor(w, 8);                         \
      if (col == 0)                                                         \
        out[tokBase + (RTI) * 16 + g * 4 + r] =                             \
            w * __builtin_amdgcn_rcpf(s) * 0.125f + b2v;                    \
    }                                                                       \
  } while (0)

  STORE_RT(0, ss_0, ww_0);
  STORE_RT(1, ss_1, ww_1);
  STORE_RT(2, ss_2, ww_2);
  STORE_RT(3, ss_3, ww_3);
#undef STORE_RT
}

extern "C" void kernel_launch(void* const* d_in, const int* in_sizes, int n_in,
                              void* d_out, int out_size, void* d_ws, size_t ws_size,
                              hipStream_t stream) {
  const float* x         = (const float*)d_in[0];
  const float* W_embed   = (const float*)d_in[1];
  const float* b_embed   = (const float*)d_in[2];
  const float* emb_table = (const float*)d_in[3];
  const float* centroids = (const float*)d_in[4];
  const float* W2        = (const float*)d_in[5];
  const float* b2        = (const float*)d_in[6];
  float* out = (float*)d_out;

  float* pre = (float*)d_ws;                               // 512 floats
  _Float16* cent_hswz = (_Float16*)((char*)d_ws + 2048);   // 256*64 f16

  precompute_kernel<<<1, NCLUST, 0, stream>>>(centroids, W2, pre);
  split_kernel<<<(NCLUST * 8) / 256, 256, 0, stream>>>(centroids, cent_hswz);
  const int tokPerBlk = 4 * 16 * RT;  // 256
  main_kernel<<<NTOK / tokPerBlk, BLK, 32768, stream>>>(
      x, W_embed, b_embed, emb_table, b2, pre, cent_hswz, out);
}

// Round 15
// 52.312 us; speedup vs baseline: 1.6849x; 1.0368x over previous
//
#include <hip/hip_runtime.h>

// Problem constants
#define NTOK   (64 * 4096)   // B*S tokens
#define DDIM   64            // num_dim
#define NCLUST 256           // num_clusters
#define NFEAT  7             // continuous features
#define BLK    256           // threads per block (4 waves)
// RT=1: 16 tokens per wave, 64 per block ; grid = 4096

typedef _Float16 f16x8 __attribute__((ext_vector_type(8)));
typedef float    f32x4 __attribute__((ext_vector_type(4)));

// -2 * (log2 e)^2 : folds softmax exp into exp2 and the -2 dot factor
#define KNEG2K (-4.1627379924399795f)

// ws layout: [0, 2048) float pre[512] = c2[256] ++ cw[256]
//            [2048, 2048+32768) _Float16 cent_hswz[256*64]   (f16-hi ONLY)
// cent_hswz row c: 8 chunks of 8 halves (16B); chunk j = f16(cent[c][j*8..+8))
// stored at chunk position (j ^ (c&7))  [XOR swizzle; 0 conflicts measured R13]

// ---- kernel 1a: per-cluster c2 / cw (verified R3..R14, verbatim) ----
__global__ __launch_bounds__(NCLUST) void precompute_kernel(
    const float* __restrict__ centroids,
    const float* __restrict__ W2,
    float* __restrict__ pre) {
  const int c = threadIdx.x;
  const float4* cp = (const float4*)(centroids + c * DDIM);
  const float4* wp = (const float4*)W2;
  float c2a = 0.f, c2b = 0.f, cwa = 0.f, cwb = 0.f;
#pragma unroll
  for (int i = 0; i < DDIM / 4; i += 2) {
    float4 v0 = cp[i], v1 = cp[i + 1];
    float4 w0 = wp[i], w1 = wp[i + 1];
    c2a = fmaf(v0.x, v0.x, fmaf(v0.y, v0.y, fmaf(v0.z, v0.z, fmaf(v0.w, v0.w, c2a))));
    c2b = fmaf(v1.x, v1.x, fmaf(v1.y, v1.y, fmaf(v1.z, v1.z, fmaf(v1.w, v1.w, c2b))));
    cwa = fmaf(v0.x, w0.x, fmaf(v0.y, w0.y, fmaf(v0.z, w0.z, fmaf(v0.w, w0.w, cwa))));
    cwb = fmaf(v1.x, w1.x, fmaf(v1.y, w1.y, fmaf(v1.z, w1.z, fmaf(v1.w, w1.w, cwb))));
  }
  pre[c] = c2a + c2b;
  pre[NCLUST + c] = cwa + cwb;
}

// ---- kernel 1b: f16-hi split -> XOR-swizzled chunk layout (verified R13) ----
__global__ __launch_bounds__(256) void split_kernel(
    const float* __restrict__ centroids,
    _Float16* __restrict__ cent_hswz) {
  const int tid = blockIdx.x * 256 + threadIdx.x;  // 0..2047
  const int c = tid >> 3;
  const int j = tid & 7;
  const int d0 = j * 8;
  f16x8 v;
#pragma unroll
  for (int i = 0; i < 8; ++i)
    v[i] = (_Float16)centroids[c * DDIM + d0 + i];
  *(f16x8*)&cent_hswz[c * 64 + (j ^ (c & 7)) * 8] = v;
}

// ---- kernel 2: fused main kernel ----
// RT=1: wave = 16 tokens x 256 clusters; 4 waves/block; grid 4096.
// __launch_bounds__(256,4): empirical cap = 256/N = 64 VGPR -> HW allows
// 8 waves/SIMD. R14 evidence: residency pinned ~1.5 waves/SIMD at nominal
// cap 128 (suspect unified-file AGPR footprint not in VGPR_Count). RT=1
// shrinks true footprint (~55-60 regs) to genuinely fit 64.
// LDS 32KB -> 5 blocks/CU = 20 waves/CU potential (62%).
__global__ __launch_bounds__(BLK, 4) void main_kernel(
    const float* __restrict__ x,
    const float* __restrict__ W_embed,
    const float* __restrict__ b_embed,
    const float* __restrict__ emb_table,
    const float* __restrict__ b2,
    const float* __restrict__ pre,
    const _Float16* __restrict__ cent_hswz,
    float* __restrict__ out) {
  extern __shared__ _Float16 s_cent[];   // 256*64 halves = 32768 B

  const int tid  = threadIdx.x;
  const int lane = tid & 63;
  const int wv   = tid >> 6;          // wave in block: 0..3
  const int col  = lane & 15;         // A-row (token) / B,C-col (cluster)
  const int g    = lane >> 4;         // k-group (0..3)
  const int tokBase = blockIdx.x * 64 + wv * 16;
  const int tok = tokBase + col;

  // ---- stage cent_hswz (32KB) -> LDS ----
  {
    const float4* gsrc = (const float4*)cent_hswz;   // 2048 float4
    float4* ldst = (float4*)s_cent;
#pragma unroll
    for (int i = 0; i < 8; ++i)
      ldst[tid + BLK * i] = gsrc[tid + BLK * i];
  }

  // ---- prologue: token features ----
  const float4* xp = (const float4*)(x + (size_t)tok * 8);
  const float4 xa = xp[0], xb = xp[1];
  const float xf[NFEAT] = {xa.x, xa.y, xa.z, xa.w, xb.x, xb.y, xb.z};
  const int idx = (int)xb.w;

  // ---- h for this lane's fragment dims: [g*8..+8) and [32+g*8..+8) ----
  float h0[8], h1[8];
  {
    const float4* er = (const float4*)(emb_table + (size_t)idx * DDIM);
    const float4* br = (const float4*)b_embed;
    float4 e0 = er[2 * g], e1 = er[2 * g + 1], e2 = er[8 + 2 * g], e3 = er[8 + 2 * g + 1];
    float4 q0 = br[2 * g], q1 = br[2 * g + 1], q2 = br[8 + 2 * g], q3 = br[8 + 2 * g + 1];
    h0[0] = e0.x + q0.x; h0[1] = e0.y + q0.y; h0[2] = e0.z + q0.z; h0[3] = e0.w + q0.w;
    h0[4] = e1.x + q1.x; h0[5] = e1.y + q1.y; h0[6] = e1.z + q1.z; h0[7] = e1.w + q1.w;
    h1[0] = e2.x + q2.x; h1[1] = e2.y + q2.y; h1[2] = e2.z + q2.z; h1[3] = e2.w + q2.w;
    h1[4] = e3.x + q3.x; h1[5] = e3.y + q3.y; h1[6] = e3.z + q3.z; h1[7] = e3.w + q3.w;
  }
#pragma unroll
  for (int f = 0; f < NFEAT; ++f) {
    const float4* wr = (const float4*)(W_embed + f * DDIM);
    const float xv = xf[f];
    float4 w0 = wr[2 * g], w1 = wr[2 * g + 1], w2 = wr[8 + 2 * g], w3 = wr[8 + 2 * g + 1];
    h0[0] = fmaf(xv, w0.x, h0[0]); h0[1] = fmaf(xv, w0.y, h0[1]);
    h0[2] = fmaf(xv, w0.z, h0[2]); h0[3] = fmaf(xv, w0.w, h0[3]);
    h0[4] = fmaf(xv, w1.x, h0[4]); h0[5] = fmaf(xv, w1.y, h0[5]);
    h0[6] = fmaf(xv, w1.z, h0[6]); h0[7] = fmaf(xv, w1.w, h0[7]);
    h1[0] = fmaf(xv, w2.x, h1[0]); h1[1] = fmaf(xv, w2.y, h1[1]);
    h1[2] = fmaf(xv, w2.z, h1[2]); h1[3] = fmaf(xv, w2.w, h1[3]);
    h1[4] = fmaf(xv, w3.x, h1[4]); h1[5] = fmaf(xv, w3.y, h1[5]);
    h1[6] = fmaf(xv, w3.z, h1[6]); h1[7] = fmaf(xv, w3.w, h1[7]);
  }

  // ---- h2 reduce (pre-scaled by -0.5) + f16 hi/lo split ----
  float ptl = 0.f;
#pragma unroll
  for (int i = 0; i < 8; ++i) {
    ptl = fmaf(h0[i], h0[i], ptl);
    ptl = fmaf(h1[i], h1[i], ptl);
  }
  ptl += __shfl_xor(ptl, 16);
  ptl += __shfl_xor(ptl, 32);
  ptl *= -0.5f;
  float nhb[4];
#pragma unroll
  for (int r = 0; r < 4; ++r) nhb[r] = __shfl(ptl, g * 4 + r);

  f16x8 ah0, al0, ah1, al1;
#pragma unroll
  for (int i = 0; i < 8; ++i) {
    _Float16 t0 = (_Float16)h0[i];
    ah0[i] = t0; al0[i] = (_Float16)(h0[i] - (float)t0);
    _Float16 t1 = (_Float16)h1[i];
    ah1[i] = t1; al1[i] = (_Float16)(h1[i] - (float)t1);
  }

  __syncthreads();   // LDS stage complete

  // ---- loop-invariant LDS addressing (sw = (t*16+col)&7 = col&7) ----
  const int sw  = col & 7;
  const _Float16* base0 = s_cent + col * 64 + ((g) ^ sw) * 8;       // chunk a
  const _Float16* base1 = s_cent + col * 64 + ((4 + g) ^ sw) * 8;   // chunk b
  const float* pc2 = pre + col;            // c2[t*16+col] (global, L1)
  const float* pcw = pre + NCLUST + col;   // cw[...]

  float ss[4] = {0.f, 0.f, 0.f, 0.f};
  float ww[4] = {0.f, 0.f, 0.f, 0.f};

#pragma unroll 2
  for (int t = 0; t < 16; ++t) {
    const f16x8 bh0 = *(const f16x8*)(base0 + t * 1024);   // 16 clusters*64 halves
    const f16x8 bh1 = *(const f16x8*)(base1 + t * 1024);
    const float c2c = pc2[t * 16];
    const float cwc = pcw[t * 16];

    f32x4 hh;
    hh[0] = fmaf(-0.5f, c2c, nhb[0]);
    hh[1] = fmaf(-0.5f, c2c, nhb[1]);
    hh[2] = fmaf(-0.5f, c2c, nhb[2]);
    hh[3] = fmaf(-0.5f, c2c, nhb[3]);
    f32x4 lh = {0.f, 0.f, 0.f, 0.f};
    hh = __builtin_amdgcn_mfma_f32_16x16x32_f16(ah0, bh0, hh, 0, 0, 0);
    lh = __builtin_amdgcn_mfma_f32_16x16x32_f16(al0, bh0, lh, 0, 0, 0);
    hh = __builtin_amdgcn_mfma_f32_16x16x32_f16(ah1, bh1, hh, 0, 0, 0);
    lh = __builtin_amdgcn_mfma_f32_16x16x32_f16(al1, bh1, lh, 0, 0, 0);
#pragma unroll
    for (int r = 0; r < 4; ++r) {
      const float m = hh[r] + lh[r];            // h.c_hi - (h2+c2)/2
      const float d2s = fmaxf(m * KNEG2K, 0.f); // (dist*log2e)^2
      const float dsc = __builtin_amdgcn_sqrtf(d2s);   // v_sqrt_f32
      const float e = __builtin_amdgcn_exp2f(-dsc);    // v_exp_f32
      ss[r] += e;
      ww[r] = fmaf(e, cwc, ww[r]);
    }
  }

  // ---- reduce over the 16 cluster-lanes, store 16 tokens per wave ----
  const float b2v = b2[0];
#pragma unroll
  for (int r = 0; r < 4; ++r) {
    float s = ss[r], w = ww[r];
    s += __shfl_xor(s, 1); w += __shfl_xor(w, 1);
    s += __shfl_xor(s, 2); w += __shfl_xor(w, 2);
    s += __shfl_xor(s, 4); w += __shfl_xor(w, 4);
    s += __shfl_xor(s, 8); w += __shfl_xor(w, 8);
    if (col == 0)
      out[tokBase + g * 4 + r] = w * __builtin_amdgcn_rcpf(s) * 0.125f + b2v;
  }
}

extern "C" void kernel_launch(void* const* d_in, const int* in_sizes, int n_in,
                              void* d_out, int out_size, void* d_ws, size_t ws_size,
                              hipStream_t stream) {
  const float* x         = (const float*)d_in[0];
  const float* W_embed   = (const float*)d_in[1];
  const float* b_embed   = (const float*)d_in[2];
  const float* emb_table = (const float*)d_in[3];
  const float* centroids = (const float*)d_in[4];
  const float* W2        = (const float*)d_in[5];
  const float* b2        = (const float*)d_in[6];
  float* out = (float*)d_out;

  float* pre = (float*)d_ws;                               // 512 floats
  _Float16* cent_hswz = (_Float16*)((char*)d_ws + 2048);   // 256*64 f16

  precompute_kernel<<<1, NCLUST, 0, stream>>>(centroids, W2, pre);
  split_kernel<<<(NCLUST * 8) / 256, 256, 0, stream>>>(centroids, cent_hswz);
  main_kernel<<<NTOK / 64, BLK, 32768, stream>>>(
      x, W_embed, b_embed, emb_table, b2, pre, cent_hswz, out);
}

// Round 16
// 50.429 us; speedup vs baseline: 1.7478x; 1.0373x over previous
//
#include <hip/hip_runtime.h>

// Problem constants
#define NTOK   (64 * 4096)   // B*S tokens
#define DDIM   64            // num_dim
#define NCLUST 256           // num_clusters
#define NFEAT  7             // continuous features
#define BLK    256           // threads per block (4 waves)
// RT=1: 16 tokens per wave, 64 per block ; grid = 4096

typedef _Float16 f16x8 __attribute__((ext_vector_type(8)));
typedef float    f32x4 __attribute__((ext_vector_type(4)));

// -2 * (log2 e)^2 : folds softmax exp into exp2 and the -2 dot factor
#define KNEG2K (-4.1627379924399795f)

// ws layout: [0, 2048) float pre[512] = c2[256] ++ cw[256]
//            [2048, 2048+32768) _Float16 cent_hswz[256*64]   (f16-hi ONLY)
// cent_hswz row c: 8 chunks of 8 halves (16B); chunk j = f16(cent[c][j*8..+8))
// stored at chunk position (j ^ (c&7))  [XOR swizzle; 0 conflicts measured R13]
// LDS layout: s_cent[256*64] halves (32768B) ++ s_pre[512] floats (2048B)

// ---- kernel 1a: per-cluster c2 / cw (verified R3..R15, verbatim) ----
__global__ __launch_bounds__(NCLUST) void precompute_kernel(
    const float* __restrict__ centroids,
    const float* __restrict__ W2,
    float* __restrict__ pre) {
  const int c = threadIdx.x;
  const float4* cp = (const float4*)(centroids + c * DDIM);
  const float4* wp = (const float4*)W2;
  float c2a = 0.f, c2b = 0.f, cwa = 0.f, cwb = 0.f;
#pragma unroll
  for (int i = 0; i < DDIM / 4; i += 2) {
    float4 v0 = cp[i], v1 = cp[i + 1];
    float4 w0 = wp[i], w1 = wp[i + 1];
    c2a = fmaf(v0.x, v0.x, fmaf(v0.y, v0.y, fmaf(v0.z, v0.z, fmaf(v0.w, v0.w, c2a))));
    c2b = fmaf(v1.x, v1.x, fmaf(v1.y, v1.y, fmaf(v1.z, v1.z, fmaf(v1.w, v1.w, c2b))));
    cwa = fmaf(v0.x, w0.x, fmaf(v0.y, w0.y, fmaf(v0.z, w0.z, fmaf(v0.w, w0.w, cwa))));
    cwb = fmaf(v1.x, w1.x, fmaf(v1.y, w1.y, fmaf(v1.z, w1.z, fmaf(v1.w, w1.w, cwb))));
  }
  pre[c] = c2a + c2b;
  pre[NCLUST + c] = cwa + cwb;
}

// ---- kernel 1b: f16-hi split -> XOR-swizzled chunk layout (verified R13) ----
__global__ __launch_bounds__(256) void split_kernel(
    const float* __restrict__ centroids,
    _Float16* __restrict__ cent_hswz) {
  const int tid = blockIdx.x * 256 + threadIdx.x;  // 0..2047
  const int c = tid >> 3;
  const int j = tid & 7;
  const int d0 = j * 8;
  f16x8 v;
#pragma unroll
  for (int i = 0; i < 8; ++i)
    v[i] = (_Float16)centroids[c * DDIM + d0 + i];
  *(f16x8*)&cent_hswz[c * 64 + (j ^ (c & 7)) * 8] = v;
}

// ---- kernel 2: fused main kernel ----
// RT=1, 4 waves/block, grid 4096. R16: pre[512] staged into LDS too ->
// the K-loop has ZERO global loads (R15 audit: 2 global pre-loads/tile,
// ~200cyc L1 latency each, were the last un-hidden VMEM stall; per-wave
// issue 2.8k cyc vs 22.6k wall = 8x stall factor). ds_read_b32 of s_pre
// is 4-lane same-address broadcast across g-groups -> conflict-free.
__global__ __launch_bounds__(BLK, 4) void main_kernel(
    const float* __restrict__ x,
    const float* __restrict__ W_embed,
    const float* __restrict__ b_embed,
    const float* __restrict__ emb_table,
    const float* __restrict__ b2,
    const float* __restrict__ pre,
    const _Float16* __restrict__ cent_hswz,
    float* __restrict__ out) {
  extern __shared__ _Float16 s_cent[];             // 256*64 halves = 32768 B
  float* s_pre = (float*)(s_cent + NCLUST * 64);   // 512 floats = 2048 B

  const int tid  = threadIdx.x;
  const int lane = tid & 63;
  const int wv   = tid >> 6;          // wave in block: 0..3
  const int col  = lane & 15;         // A-row (token) / B,C-col (cluster)
  const int g    = lane >> 4;         // k-group (0..3)
  const int tokBase = blockIdx.x * 64 + wv * 16;
  const int tok = tokBase + col;

  // ---- stage cent_hswz (32KB) + pre (2KB) -> LDS ----
  {
    const float4* gsrc = (const float4*)cent_hswz;   // 2048 float4
    float4* ldst = (float4*)s_cent;
#pragma unroll
    for (int i = 0; i < 8; ++i)
      ldst[tid + BLK * i] = gsrc[tid + BLK * i];
    s_pre[tid] = pre[tid];
    s_pre[tid + 256] = pre[tid + 256];
  }

  // ---- prologue: token features ----
  const float4* xp = (const float4*)(x + (size_t)tok * 8);
  const float4 xa = xp[0], xb = xp[1];
  const float xf[NFEAT] = {xa.x, xa.y, xa.z, xa.w, xb.x, xb.y, xb.z};
  const int idx = (int)xb.w;

  // ---- h for this lane's fragment dims: [g*8..+8) and [32+g*8..+8) ----
  float h0[8], h1[8];
  {
    const float4* er = (const float4*)(emb_table + (size_t)idx * DDIM);
    const float4* br = (const float4*)b_embed;
    float4 e0 = er[2 * g], e1 = er[2 * g + 1], e2 = er[8 + 2 * g], e3 = er[8 + 2 * g + 1];
    float4 q0 = br[2 * g], q1 = br[2 * g + 1], q2 = br[8 + 2 * g], q3 = br[8 + 2 * g + 1];
    h0[0] = e0.x + q0.x; h0[1] = e0.y + q0.y; h0[2] = e0.z + q0.z; h0[3] = e0.w + q0.w;
    h0[4] = e1.x + q1.x; h0[5] = e1.y + q1.y; h0[6] = e1.z + q1.z; h0[7] = e1.w + q1.w;
    h1[0] = e2.x + q2.x; h1[1] = e2.y + q2.y; h1[2] = e2.z + q2.z; h1[3] = e2.w + q2.w;
    h1[4] = e3.x + q3.x; h1[5] = e3.y + q3.y; h1[6] = e3.z + q3.z; h1[7] = e3.w + q3.w;
  }
#pragma unroll
  for (int f = 0; f < NFEAT; ++f) {
    const float4* wr = (const float4*)(W_embed + f * DDIM);
    const float xv = xf[f];
    float4 w0 = wr[2 * g], w1 = wr[2 * g + 1], w2 = wr[8 + 2 * g], w3 = wr[8 + 2 * g + 1];
    h0[0] = fmaf(xv, w0.x, h0[0]); h0[1] = fmaf(xv, w0.y, h0[1]);
    h0[2] = fmaf(xv, w0.z, h0[2]); h0[3] = fmaf(xv, w0.w, h0[3]);
    h0[4] = fmaf(xv, w1.x, h0[4]); h0[5] = fmaf(xv, w1.y, h0[5]);
    h0[6] = fmaf(xv, w1.z, h0[6]); h0[7] = fmaf(xv, w1.w, h0[7]);
    h1[0] = fmaf(xv, w2.x, h1[0]); h1[1] = fmaf(xv, w2.y, h1[1]);
    h1[2] = fmaf(xv, w2.z, h1[2]); h1[3] = fmaf(xv, w2.w, h1[3]);
    h1[4] = fmaf(xv, w3.x, h1[4]); h1[5] = fmaf(xv, w3.y, h1[5]);
    h1[6] = fmaf(xv, w3.z, h1[6]); h1[7] = fmaf(xv, w3.w, h1[7]);
  }

  // ---- h2 reduce (pre-scaled by -0.5) + f16 hi/lo split ----
  float ptl = 0.f;
#pragma unroll
  for (int i = 0; i < 8; ++i) {
    ptl = fmaf(h0[i], h0[i], ptl);
    ptl = fmaf(h1[i], h1[i], ptl);
  }
  ptl += __shfl_xor(ptl, 16);
  ptl += __shfl_xor(ptl, 32);
  ptl *= -0.5f;
  float nhb[4];
#pragma unroll
  for (int r = 0; r < 4; ++r) nhb[r] = __shfl(ptl, g * 4 + r);

  f16x8 ah0, al0, ah1, al1;
#pragma unroll
  for (int i = 0; i < 8; ++i) {
    _Float16 t0 = (_Float16)h0[i];
    ah0[i] = t0; al0[i] = (_Float16)(h0[i] - (float)t0);
    _Float16 t1 = (_Float16)h1[i];
    ah1[i] = t1; al1[i] = (_Float16)(h1[i] - (float)t1);
  }

  __syncthreads();   // LDS stage complete

  // ---- loop-invariant LDS addressing (sw = (t*16+col)&7 = col&7) ----
  const int sw  = col & 7;
  const _Float16* base0 = s_cent + col * 64 + ((g) ^ sw) * 8;       // chunk a
  const _Float16* base1 = s_cent + col * 64 + ((4 + g) ^ sw) * 8;   // chunk b
  const float* pc2 = s_pre + col;          // c2[t*16+col] at +t*64B (LDS)
  const float* pcw = s_pre + NCLUST + col; // cw[...]

  float ss[4] = {0.f, 0.f, 0.f, 0.f};
  float ww[4] = {0.f, 0.f, 0.f, 0.f};

#pragma unroll 2
  for (int t = 0; t < 16; ++t) {
    const f16x8 bh0 = *(const f16x8*)(base0 + t * 1024);   // 16 clusters*64 halves
    const f16x8 bh1 = *(const f16x8*)(base1 + t * 1024);
    const float c2c = pc2[t * 16];
    const float cwc = pcw[t * 16];

    f32x4 hh;
    hh[0] = fmaf(-0.5f, c2c, nhb[0]);
    hh[1] = fmaf(-0.5f, c2c, nhb[1]);
    hh[2] = fmaf(-0.5f, c2c, nhb[2]);
    hh[3] = fmaf(-0.5f, c2c, nhb[3]);
    f32x4 lh = {0.f, 0.f, 0.f, 0.f};
    hh = __builtin_amdgcn_mfma_f32_16x16x32_f16(ah0, bh0, hh, 0, 0, 0);
    lh = __builtin_amdgcn_mfma_f32_16x16x32_f16(al0, bh0, lh, 0, 0, 0);
    hh = __builtin_amdgcn_mfma_f32_16x16x32_f16(ah1, bh1, hh, 0, 0, 0);
    lh = __builtin_amdgcn_mfma_f32_16x16x32_f16(al1, bh1, lh, 0, 0, 0);
#pragma unroll
    for (int r = 0; r < 4; ++r) {
      const float m = hh[r] + lh[r];            // h.c_hi - (h2+c2)/2
      const float d2s = fmaxf(m * KNEG2K, 0.f); // (dist*log2e)^2
      const float dsc = __builtin_amdgcn_sqrtf(d2s);   // v_sqrt_f32
      const float e = __builtin_amdgcn_exp2f(-dsc);    // v_exp_f32
      ss[r] += e;
      ww[r] = fmaf(e, cwc, ww[r]);
    }
  }

  // ---- reduce over the 16 cluster-lanes, store 16 tokens per wave ----
  const float b2v = b2[0];
#pragma unroll
  for (int r = 0; r < 4; ++r) {
    float s = ss[r], w = ww[r];
    s += __shfl_xor(s, 1); w += __shfl_xor(w, 1);
    s += __shfl_xor(s, 2); w += __shfl_xor(w, 2);
    s += __shfl_xor(s, 4); w += __shfl_xor(w, 4);
    s += __shfl_xor(s, 8); w += __shfl_xor(w, 8);
    if (col == 0)
      out[tokBase + g * 4 + r] = w * __builtin_amdgcn_rcpf(s) * 0.125f + b2v;
  }
}

extern "C" void kernel_launch(void* const* d_in, const int* in_sizes, int n_in,
                              void* d_out, int out_size, void* d_ws, size_t ws_size,
                              hipStream_t stream) {
  const float* x         = (const float*)d_in[0];
  const float* W_embed   = (const float*)d_in[1];
  const float* b_embed   = (const float*)d_in[2];
  const float* emb_table = (const float*)d_in[3];
  const float* centroids = (const float*)d_in[4];
  const float* W2        = (const float*)d_in[5];
  const float* b2        = (const float*)d_in[6];
  float* out = (float*)d_out;

  float* pre = (float*)d_ws;                               // 512 floats
  _Float16* cent_hswz = (_Float16*)((char*)d_ws + 2048);   // 256*64 f16

  precompute_kernel<<<1, NCLUST, 0, stream>>>(centroids, W2, pre);
  split_kernel<<<(NCLUST * 8) / 256, 256, 0, stream>>>(centroids, cent_hswz);
  main_kernel<<<NTOK / 64, BLK, 32768 + 2048, stream>>>(
      x, W_embed, b_embed, emb_table, b2, pre, cent_hswz, out);
}

// Round 17
// 46.726 us; speedup vs baseline: 1.8863x; 1.0792x over previous
//
#include <hip/hip_runtime.h>

// Problem constants
#define NTOK   (64 * 4096)   // B*S tokens
#define DDIM   64            // num_dim
#define NCLUST 256           // num_clusters
#define NFEAT  7             // continuous features
#define RT     2             // row-tiles of 16 tokens per wave
#define BLK    256           // threads per block (4 waves)
// tokens per block = 4 waves * RT*16 = 128 ; grid = 2048

typedef _Float16 f16x8 __attribute__((ext_vector_type(8)));
typedef float    f32x4 __attribute__((ext_vector_type(4)));

// -2 * (log2 e)^2 : folds softmax exp into exp2 and the -2 dot factor
#define KNEG2K (-4.1627379924399795f)

// ws layout: [0, 2048) float pre[512] = c2[256] ++ cw[256]
//            [2048, 2048+32768) _Float16 cent_hswz[256*64]   (f16-hi ONLY)
// cent_hswz row c: 8 chunks of 8 halves (16B); chunk j = f16(cent[c][j*8..+8))
// stored at chunk position (j ^ (c&7))  [XOR swizzle; 0 conflicts measured R13]
// LDS: s_cent[256*64] halves (32768B) ++ s_pre[512] floats (2048B)

// ---- kernel 1a: per-cluster c2 / cw (verified R3..R16, verbatim) ----
__global__ __launch_bounds__(NCLUST) void precompute_kernel(
    const float* __restrict__ centroids,
    const float* __restrict__ W2,
    float* __restrict__ pre) {
  const int c = threadIdx.x;
  const float4* cp = (const float4*)(centroids + c * DDIM);
  const float4* wp = (const float4*)W2;
  float c2a = 0.f, c2b = 0.f, cwa = 0.f, cwb = 0.f;
#pragma unroll
  for (int i = 0; i < DDIM / 4; i += 2) {
    float4 v0 = cp[i], v1 = cp[i + 1];
    float4 w0 = wp[i], w1 = wp[i + 1];
    c2a = fmaf(v0.x, v0.x, fmaf(v0.y, v0.y, fmaf(v0.z, v0.z, fmaf(v0.w, v0.w, c2a))));
    c2b = fmaf(v1.x, v1.x, fmaf(v1.y, v1.y, fmaf(v1.z, v1.z, fmaf(v1.w, v1.w, c2b))));
    cwa = fmaf(v0.x, w0.x, fmaf(v0.y, w0.y, fmaf(v0.z, w0.z, fmaf(v0.w, w0.w, cwa))));
    cwb = fmaf(v1.x, w1.x, fmaf(v1.y, w1.y, fmaf(v1.z, w1.z, fmaf(v1.w, w1.w, cwb))));
  }
  pre[c] = c2a + c2b;
  pre[NCLUST + c] = cwa + cwb;
}

// ---- kernel 1b: f16-hi split -> XOR-swizzled chunk layout (verified R13) ----
__global__ __launch_bounds__(256) void split_kernel(
    const float* __restrict__ centroids,
    _Float16* __restrict__ cent_hswz) {
  const int tid = blockIdx.x * 256 + threadIdx.x;  // 0..2047
  const int c = tid >> 3;
  const int j = tid & 7;
  const int d0 = j * 8;
  f16x8 v;
#pragma unroll
  for (int i = 0; i < 8; ++i)
    v[i] = (_Float16)centroids[c * DDIM + d0 + i];
  *(f16x8*)&cent_hswz[c * 64 + (j ^ (c & 7)) * 8] = v;
}

// ---- kernel 2: fused main kernel ----
// RT=2, 4 waves/block (256 thr), wave = 32 tokens x 256 clusters; grid 2048.
// R17: halve per-CU LDS traffic (R16 audit: LDS = 15us, largest pipe floor;
// every wave re-reads the 32KB table, so tokens-per-wave x2 => traffic /2)
// + 8 independent epilogue streams/wave. (256,3) => 85-VGPR cap (live ~76).
__global__ __launch_bounds__(BLK, 3) void main_kernel(
    const float* __restrict__ x,
    const float* __restrict__ W_embed,
    const float* __restrict__ b_embed,
    const float* __restrict__ emb_table,
    const float* __restrict__ b2,
    const float* __restrict__ pre,
    const _Float16* __restrict__ cent_hswz,
    float* __restrict__ out) {
  extern __shared__ _Float16 s_cent[];             // 256*64 halves = 32768 B
  float* s_pre = (float*)(s_cent + NCLUST * 64);   // 512 floats = 2048 B

  const int tid  = threadIdx.x;
  const int lane = tid & 63;
  const int wv   = tid >> 6;          // wave in block: 0..3
  const int col  = lane & 15;         // A-row (token) / B,C-col (cluster)
  const int g    = lane >> 4;         // k-group (0..3)
  const int tokBase = blockIdx.x * (4 * 16 * RT) + wv * (16 * RT);

  // ---- stage cent_hswz (32KB) + pre (2KB) -> LDS ----
  {
    const float4* gsrc = (const float4*)cent_hswz;   // 2048 float4
    float4* ldst = (float4*)s_cent;
#pragma unroll
    for (int i = 0; i < 8; ++i)
      ldst[tid + BLK * i] = gsrc[tid + BLK * i];
    s_pre[tid] = pre[tid];
    s_pre[tid + 256] = pre[tid + 256];
  }

  // ---- b_embed fragment (token-independent) ----
  const float4* br = (const float4*)b_embed;
  const float4 q0 = br[2 * g], q1 = br[2 * g + 1];
  const float4 q2 = br[8 + 2 * g], q3 = br[8 + 2 * g + 1];

  // ---- prologue: h[rt][0..7]=dims[g*8..+8), h[rt][8..15]=dims[32+g*8..+8) ----
  float h[RT][16];
  float xf[RT][NFEAT];
#pragma unroll
  for (int rt = 0; rt < RT; ++rt) {
    const int tok = tokBase + rt * 16 + col;
    const float4* xp = (const float4*)(x + (size_t)tok * 8);
    const float4 xa = xp[0], xb = xp[1];
    xf[rt][0] = xa.x; xf[rt][1] = xa.y; xf[rt][2] = xa.z; xf[rt][3] = xa.w;
    xf[rt][4] = xb.x; xf[rt][5] = xb.y; xf[rt][6] = xb.z;
    const int idx = (int)xb.w;
    const float4* er = (const float4*)(emb_table + (size_t)idx * DDIM);
    const float4 e0 = er[2 * g], e1 = er[2 * g + 1];
    const float4 e2 = er[8 + 2 * g], e3 = er[8 + 2 * g + 1];
    h[rt][0]  = e0.x + q0.x; h[rt][1]  = e0.y + q0.y;
    h[rt][2]  = e0.z + q0.z; h[rt][3]  = e0.w + q0.w;
    h[rt][4]  = e1.x + q1.x; h[rt][5]  = e1.y + q1.y;
    h[rt][6]  = e1.z + q1.z; h[rt][7]  = e1.w + q1.w;
    h[rt][8]  = e2.x + q2.x; h[rt][9]  = e2.y + q2.y;
    h[rt][10] = e2.z + q2.z; h[rt][11] = e2.w + q2.w;
    h[rt][12] = e3.x + q3.x; h[rt][13] = e3.y + q3.y;
    h[rt][14] = e3.z + q3.z; h[rt][15] = e3.w + q3.w;
  }
  // W_embed: f outer (W fragment loaded once), rt inner
#pragma unroll
  for (int f = 0; f < NFEAT; ++f) {
    const float4* wr = (const float4*)(W_embed + f * DDIM);
    const float4 w0 = wr[2 * g], w1 = wr[2 * g + 1];
    const float4 w2 = wr[8 + 2 * g], w3 = wr[8 + 2 * g + 1];
#pragma unroll
    for (int rt = 0; rt < RT; ++rt) {
      const float xv = xf[rt][f];
      h[rt][0]  = fmaf(xv, w0.x, h[rt][0]);  h[rt][1]  = fmaf(xv, w0.y, h[rt][1]);
      h[rt][2]  = fmaf(xv, w0.z, h[rt][2]);  h[rt][3]  = fmaf(xv, w0.w, h[rt][3]);
      h[rt][4]  = fmaf(xv, w1.x, h[rt][4]);  h[rt][5]  = fmaf(xv, w1.y, h[rt][5]);
      h[rt][6]  = fmaf(xv, w1.z, h[rt][6]);  h[rt][7]  = fmaf(xv, w1.w, h[rt][7]);
      h[rt][8]  = fmaf(xv, w2.x, h[rt][8]);  h[rt][9]  = fmaf(xv, w2.y, h[rt][9]);
      h[rt][10] = fmaf(xv, w2.z, h[rt][10]); h[rt][11] = fmaf(xv, w2.w, h[rt][11]);
      h[rt][12] = fmaf(xv, w3.x, h[rt][12]); h[rt][13] = fmaf(xv, w3.y, h[rt][13]);
      h[rt][14] = fmaf(xv, w3.z, h[rt][14]); h[rt][15] = fmaf(xv, w3.w, h[rt][15]);
    }
  }

  // ---- per-rt: h2 reduce (pre-scaled by -0.5) + f16 hi/lo split, NAMED frags ----
  f16x8 ah0_0, al0_0, ah1_0, al1_0; float nhb_0[4];
  f16x8 ah0_1, al0_1, ah1_1, al1_1; float nhb_1[4];

#define SPLIT_RT(RTI, AH0, AL0, AH1, AL1, NHB) do {                         \
    float ptl = 0.f;                                                        \
    _Pragma("unroll") for (int i = 0; i < 8; ++i) {                         \
      ptl = fmaf(h[RTI][i], h[RTI][i], ptl);                                \
      ptl = fmaf(h[RTI][8 + i], h[RTI][8 + i], ptl);                        \
    }                                                                       \
    ptl += __shfl_xor(ptl, 16);                                             \
    ptl += __shfl_xor(ptl, 32);                                             \
    ptl *= -0.5f;                                                           \
    _Pragma("unroll") for (int r = 0; r < 4; ++r)                           \
      NHB[r] = __shfl(ptl, g * 4 + r);                                      \
    _Pragma("unroll") for (int i = 0; i < 8; ++i) {                         \
      _Float16 t0 = (_Float16)h[RTI][i];                                    \
      AH0[i] = t0; AL0[i] = (_Float16)(h[RTI][i] - (float)t0);              \
      _Float16 t1 = (_Float16)h[RTI][8 + i];                                \
      AH1[i] = t1; AL1[i] = (_Float16)(h[RTI][8 + i] - (float)t1);          \
    }                                                                       \
  } while (0)

  SPLIT_RT(0, ah0_0, al0_0, ah1_0, al1_0, nhb_0);
  SPLIT_RT(1, ah0_1, al0_1, ah1_1, al1_1, nhb_1);
#undef SPLIT_RT

  __syncthreads();   // LDS stage complete

  // ---- loop-invariant LDS addressing (sw = (t*16+col)&7 = col&7) ----
  const int sw  = col & 7;
  const _Float16* base0 = s_cent + col * 64 + ((g) ^ sw) * 8;       // chunk a
  const _Float16* base1 = s_cent + col * 64 + ((4 + g) ^ sw) * 8;   // chunk b
  const float* pc2 = s_pre + col;          // c2[t*16+col] at +t*64B (LDS)
  const float* pcw = s_pre + NCLUST + col; // cw[...]

  float ss_0[4] = {0.f, 0.f, 0.f, 0.f}, ww_0[4] = {0.f, 0.f, 0.f, 0.f};
  float ss_1[4] = {0.f, 0.f, 0.f, 0.f}, ww_1[4] = {0.f, 0.f, 0.f, 0.f};

#pragma unroll 2
  for (int t = 0; t < 16; ++t) {
    const f16x8 bh0 = *(const f16x8*)(base0 + t * 1024);   // 16 clusters*64 halves
    const f16x8 bh1 = *(const f16x8*)(base1 + t * 1024);
    const float c2c = pc2[t * 16];
    const float cwc = pcw[t * 16];

#define DO_RT(AH0, AL0, AH1, AL1, NHB, SS, WW) do {                         \
    f32x4 hh;                                                               \
    hh[0] = fmaf(-0.5f, c2c, NHB[0]);                                       \
    hh[1] = fmaf(-0.5f, c2c, NHB[1]);                                       \
    hh[2] = fmaf(-0.5f, c2c, NHB[2]);                                       \
    hh[3] = fmaf(-0.5f, c2c, NHB[3]);                                       \
    f32x4 lh = {0.f, 0.f, 0.f, 0.f};                                        \
    hh = __builtin_amdgcn_mfma_f32_16x16x32_f16(AH0, bh0, hh, 0, 0, 0);     \
    lh = __builtin_amdgcn_mfma_f32_16x16x32_f16(AL0, bh0, lh, 0, 0, 0);     \
    hh = __builtin_amdgcn_mfma_f32_16x16x32_f16(AH1, bh1, hh, 0, 0, 0);     \
    lh = __builtin_amdgcn_mfma_f32_16x16x32_f16(AL1, bh1, lh, 0, 0, 0);     \
    _Pragma("unroll") for (int r = 0; r < 4; ++r) {                         \
      const float m = hh[r] + lh[r];            /* h.c_hi - (h2+c2)/2 */    \
      const float d2s = fmaxf(m * KNEG2K, 0.f); /* (dist*log2e)^2 */        \
      const float dsc = __builtin_amdgcn_sqrtf(d2s);   /* v_sqrt_f32 */     \
      const float e = __builtin_amdgcn_exp2f(-dsc);    /* v_exp_f32 */      \
      SS[r] += e;                                                           \
      WW[r] = fmaf(e, cwc, WW[r]);                                          \
    }                                                                       \
  } while (0)

    DO_RT(ah0_0, al0_0, ah1_0, al1_0, nhb_0, ss_0, ww_0);
    DO_RT(ah0_1, al0_1, ah1_1, al1_1, nhb_1, ss_1, ww_1);
#undef DO_RT
  }

  // ---- reduce over the 16 cluster-lanes, store 32 tokens per wave ----
  const float b2v = b2[0];
#define STORE_RT(RTI, SS, WW) do {                                          \
    _Pragma("unroll") for (int r = 0; r < 4; ++r) {                         \
      float s = SS[r], w = WW[r];                                           \
      s += __shfl_xor(s, 1); w += __shfl_xor(w, 1);                         \
      s += __shfl_xor(s, 2); w += __shfl_xor(w, 2);                         \
      s += __shfl_xor(s, 4); w += __shfl_xor(w, 4);                         \
      s += __shfl_xor(s, 8); w += __shfl_xor(w, 8);                         \
      if (col == 0)                                                         \
        out[tokBase + (RTI) * 16 + g * 4 + r] =                             \
            w * __builtin_amdgcn_rcpf(s) * 0.125f + b2v;                    \
    }                                                                       \
  } while (0)

  STORE_RT(0, ss_0, ww_0);
  STORE_RT(1, ss_1, ww_1);
#undef STORE_RT
}

extern "C" void kernel_launch(void* const* d_in, const int* in_sizes, int n_in,
                              void* d_out, int out_size, void* d_ws, size_t ws_size,
                              hipStream_t stream) {
  const float* x         = (const float*)d_in[0];
  const float* W_embed   = (const float*)d_in[1];
  const float* b_embed   = (const float*)d_in[2];
  const float* emb_table = (const float*)d_in[3];
  const float* centroids = (const float*)d_in[4];
  const float* W2        = (const float*)d_in[5];
  const float* b2        = (const float*)d_in[6];
  float* out = (float*)d_out;

  float* pre = (float*)d_ws;                               // 512 floats
  _Float16* cent_hswz = (_Float16*)((char*)d_ws + 2048);   // 256*64 f16

  precompute_kernel<<<1, NCLUST, 0, stream>>>(centroids, W2, pre);
  split_kernel<<<(NCLUST * 8) / 256, 256, 0, stream>>>(centroids, cent_hswz);
  const int tokPerBlk = 4 * 16 * RT;  // 128
  main_kernel<<<NTOK / tokPerBlk, BLK, 32768 + 2048, stream>>>(
      x, W_embed, b_embed, emb_table, b2, pre, cent_hswz, out);
}